// Round 1
// baseline (1836.073 us; speedup 1.0000x reference)
//
#include <hip/hip_runtime.h>

#define N_NODES 100000
#define N_EDGES 1600000
#define N_GRAPHS 512
#define F_IN 64
#define NHEAD 4
#define DHEAD 64
#define HD 256
#define EXTRA 16
#define SCAN_BLOCK 512

__device__ __forceinline__ float selu_f(float x) {
    const float a = 1.6732632423543772f, sc = 1.0507009873554805f;
    return x > 0.f ? sc * x : sc * a * (__expf(x) - 1.f);
}

// ---------------- CSR build ----------------
__global__ __launch_bounds__(256) void hist_k(const int* __restrict__ dst, int* __restrict__ hist) {
    int j = blockIdx.x * 256 + threadIdx.x;
    if (j < N_EDGES) atomicAdd(&hist[dst[j]], 1);
}

__global__ __launch_bounds__(SCAN_BLOCK) void scan1_k(const int* __restrict__ hist,
                                                      int* __restrict__ row_ptr,
                                                      int* __restrict__ bsums) {
    __shared__ int sm[SCAN_BLOCK];
    int t = threadIdx.x;
    int i = blockIdx.x * SCAN_BLOCK + t;
    int v = (i < N_NODES) ? hist[i] : 0;
    sm[t] = v;
    __syncthreads();
    for (int off = 1; off < SCAN_BLOCK; off <<= 1) {
        int add = (t >= off) ? sm[t - off] : 0;
        __syncthreads();
        sm[t] += add;
        __syncthreads();
    }
    if (i < N_NODES) row_ptr[i] = sm[t] - v;  // exclusive within block
    if (t == SCAN_BLOCK - 1) bsums[blockIdx.x] = sm[t];
}

__global__ __launch_bounds__(256) void scan2_k(int* __restrict__ bsums, int nb) {
    __shared__ int sm[256];
    int t = threadIdx.x;
    int v = (t < nb) ? bsums[t] : 0;
    sm[t] = v;
    __syncthreads();
    for (int off = 1; off < 256; off <<= 1) {
        int add = (t >= off) ? sm[t - off] : 0;
        __syncthreads();
        sm[t] += add;
        __syncthreads();
    }
    if (t < nb) bsums[t] = sm[t] - v;  // exclusive block offsets
}

__global__ __launch_bounds__(256) void scan3_k(int* __restrict__ row_ptr, const int* __restrict__ bsums) {
    int i = blockIdx.x * 256 + threadIdx.x;
    if (i < N_NODES) row_ptr[i] += bsums[i / SCAN_BLOCK];
    if (i == 0) row_ptr[N_NODES] = N_EDGES;
}

__global__ __launch_bounds__(256) void scatter_k(const int* __restrict__ dst,
                                                 const int* __restrict__ row_ptr,
                                                 int* __restrict__ cursor,
                                                 int* __restrict__ edge_idx) {
    int j = blockIdx.x * 256 + threadIdx.x;
    if (j < N_EDGES) {
        int d = dst[j];
        int r = atomicAdd(&cursor[d], 1);
        edge_idx[row_ptr[d] + r] = j;
    }
}

__global__ __launch_bounds__(256) void gbound_k(const int* __restrict__ node_graph, int* __restrict__ gstart) {
    int g = blockIdx.x * 256 + threadIdx.x;
    if (g > N_GRAPHS) return;
    int lo = 0, hi = N_NODES;
    while (lo < hi) {
        int mid = (lo + hi) >> 1;
        if (node_graph[mid] < g) lo = mid + 1; else hi = mid;
    }
    gstart[g] = lo;
}

// ---------------- GEMM: C[M,256] = A[M,K] @ Bw[K,256] ----------------
template <int K>
__global__ __launch_bounds__(256) void gemm_k(const float* __restrict__ A,
                                              const float* __restrict__ Bw,
                                              float* __restrict__ C, int M) {
    const int BM = 64, BN = 64, BK = 16;
    __shared__ float As[BK][BM + 4];
    __shared__ float Bs[BK][BN + 4];
    int tid = threadIdx.x;
    int tx = tid % 16, ty = tid / 16;
    int row0 = blockIdx.y * BM;
    int col0 = blockIdx.x * BN;
    float acc[4][4] = {};
    int a_r = tid / 4;          // 0..63
    int a_k = (tid % 4) * 4;    // 0,4,8,12
    int b_k = tid / 16;         // 0..15
    int b_n = (tid % 16) * 4;   // 0..60

    for (int k0 = 0; k0 < K; k0 += BK) {
        int ar = row0 + a_r;
        float4 av = (ar < M) ? *(const float4*)(A + (size_t)ar * K + k0 + a_k)
                             : make_float4(0.f, 0.f, 0.f, 0.f);
        As[a_k + 0][a_r] = av.x;
        As[a_k + 1][a_r] = av.y;
        As[a_k + 2][a_r] = av.z;
        As[a_k + 3][a_r] = av.w;
        float4 bv = *(const float4*)(Bw + (size_t)(k0 + b_k) * HD + col0 + b_n);
        *(float4*)&Bs[b_k][b_n] = bv;
        __syncthreads();
#pragma unroll
        for (int kk = 0; kk < BK; kk++) {
            float ra[4], rb[4];
#pragma unroll
            for (int i = 0; i < 4; i++) ra[i] = As[kk][ty * 4 + i];
#pragma unroll
            for (int j = 0; j < 4; j++) rb[j] = Bs[kk][tx * 4 + j];
#pragma unroll
            for (int i = 0; i < 4; i++)
#pragma unroll
                for (int j = 0; j < 4; j++)
                    acc[i][j] = fmaf(ra[i], rb[j], acc[i][j]);
        }
        __syncthreads();
    }
#pragma unroll
    for (int i = 0; i < 4; i++) {
        int r = row0 + ty * 4 + i;
        if (r < M) {
            float4 v = make_float4(acc[i][0], acc[i][1], acc[i][2], acc[i][3]);
            *(float4*)(C + (size_t)r * HD + col0 + tx * 4) = v;
        }
    }
}

// ---------------- per-node attention logits: el/er [N,4] ----------------
__global__ __launch_bounds__(256) void attn_logits_k(const float* __restrict__ h,
                                                     const float* __restrict__ al,
                                                     const float* __restrict__ ar,
                                                     float* __restrict__ el,
                                                     float* __restrict__ er) {
    int n = (blockIdx.x * 256 + threadIdx.x) / 64;
    int lane = threadIdx.x & 63;
    if (n >= N_NODES) return;
    float4 hv = *(const float4*)(h + (size_t)n * HD + lane * 4);
    float4 alv = *(const float4*)(al + lane * 4);
    float4 arv = *(const float4*)(ar + lane * 4);
    float pl = hv.x * alv.x + hv.y * alv.y + hv.z * alv.z + hv.w * alv.w;
    float pr = hv.x * arv.x + hv.y * arv.y + hv.z * arv.z + hv.w * arv.w;
#pragma unroll
    for (int off = 1; off < 16; off <<= 1) {
        pl += __shfl_xor(pl, off, 64);
        pr += __shfl_xor(pr, off, 64);
    }
    if ((lane & 15) == 0) {
        int head = lane >> 4;
        el[(size_t)n * 4 + head] = pl;
        er[(size_t)n * 4 + head] = pr;
    }
}

// ---------------- GAT aggregation: one wave per destination node ----------------
__global__ __launch_bounds__(256) void gat_aggregate_k(const float* __restrict__ h,
                                                       const float* __restrict__ el,
                                                       const float* __restrict__ er,
                                                       const int* __restrict__ src,
                                                       const int* __restrict__ row_ptr,
                                                       const int* __restrict__ edge_idx,
                                                       const float* __restrict__ bias,
                                                       float* __restrict__ xout) {
    int v = (blockIdx.x * 256 + threadIdx.x) / 64;
    int lane = threadIdx.x & 63;
    if (v >= N_NODES) return;
    int rs = row_ptr[v], re = row_ptr[v + 1];
    int deg = re - rs;
    float4 erv = *(const float4*)(er + (size_t)v * 4);

    // online softmax per lane over its subset of edges, then wave-combine
    float m[4] = {-1e30f, -1e30f, -1e30f, -1e30f};
    float s[4] = {0.f, 0.f, 0.f, 0.f};
    for (int t = lane; t < deg; t += 64) {
        int j = edge_idx[rs + t];
        int sn = src[j];
        float4 elv = *(const float4*)(el + (size_t)sn * 4);
        float e[4];
        e[0] = elv.x + erv.x; e[1] = elv.y + erv.y; e[2] = elv.z + erv.z; e[3] = elv.w + erv.w;
#pragma unroll
        for (int hh = 0; hh < 4; hh++) {
            float ev = e[hh] > 0.f ? e[hh] : 0.2f * e[hh];
            float mn = fmaxf(m[hh], ev);
            s[hh] = s[hh] * __expf(m[hh] - mn) + __expf(ev - mn);
            m[hh] = mn;
        }
    }
#pragma unroll
    for (int off = 32; off >= 1; off >>= 1) {
#pragma unroll
        for (int hh = 0; hh < 4; hh++) {
            float mo = __shfl_xor(m[hh], off, 64);
            float so = __shfl_xor(s[hh], off, 64);
            float mn = fmaxf(m[hh], mo);
            s[hh] = s[hh] * __expf(m[hh] - mn) + so * __expf(mo - mn);
            m[hh] = mn;
        }
    }

    int head = lane >> 4;
    float m_h = head == 0 ? m[0] : head == 1 ? m[1] : head == 2 ? m[2] : m[3];
    float den = head == 0 ? s[0] : head == 1 ? s[1] : head == 2 ? s[2] : s[3];
    float er_h = head == 0 ? erv.x : head == 1 ? erv.y : head == 2 ? erv.z : erv.w;
    float inv_den = 1.f / fmaxf(den, 1e-9f);

    float4 acc = make_float4(0.f, 0.f, 0.f, 0.f);
    for (int t = 0; t < deg; t++) {
        int j = edge_idx[rs + t];
        int sn = src[j];
        float e = el[(size_t)sn * 4 + head] + er_h;
        e = e > 0.f ? e : 0.2f * e;
        float a = __expf(e - m_h) * inv_den;
        float4 hv = *(const float4*)(h + (size_t)sn * HD + lane * 4);
        acc.x = fmaf(a, hv.x, acc.x);
        acc.y = fmaf(a, hv.y, acc.y);
        acc.z = fmaf(a, hv.z, acc.z);
        acc.w = fmaf(a, hv.w, acc.w);
    }
    float4 bv = *(const float4*)(bias + lane * 4);
    acc.x = selu_f(acc.x + bv.x);
    acc.y = selu_f(acc.y + bv.y);
    acc.z = selu_f(acc.z + bv.z);
    acc.w = selu_f(acc.w + bv.w);
    *(float4*)(xout + (size_t)v * HD + lane * 4) = acc;
}

// ---------------- readout ----------------
__global__ __launch_bounds__(256) void score_k(const float* __restrict__ x,
                                               const float* __restrict__ sw,
                                               const float* __restrict__ sb,
                                               float* __restrict__ wsc) {
    int n = (blockIdx.x * 256 + threadIdx.x) / 64;
    int lane = threadIdx.x & 63;
    if (n >= N_NODES) return;
    float4 xv = *(const float4*)(x + (size_t)n * HD + lane * 4);
    float4 sv = *(const float4*)(sw + lane * 4);
    float p = xv.x * sv.x + xv.y * sv.y + xv.z * sv.z + xv.w * sv.w;
#pragma unroll
    for (int off = 1; off < 64; off <<= 1) p += __shfl_xor(p, off, 64);
    if (lane == 0) wsc[n] = 1.f / (1.f + __expf(-(p + sb[0])));
}

__global__ __launch_bounds__(256) void readout_k(const float* __restrict__ x,
                                                 const float* __restrict__ wsc,
                                                 const int* __restrict__ gstart,
                                                 const float* __restrict__ fg,
                                                 float* __restrict__ y0) {
    int g = blockIdx.x;
    int f = threadIdx.x;
    int s = gstart[g], e = gstart[g + 1];
    float num = 0.f, den = 0.f;
    for (int n = s; n < e; n++) {
        float wn = wsc[n];
        num = fmaf(wn, x[(size_t)n * HD + f], num);
        den += wn;
    }
    float emb = num / fmaxf(den, 1e-9f);
    y0[(size_t)g * 272 + f] = emb;
    if (f < EXTRA) y0[(size_t)g * 272 + 256 + f] = fg[g * EXTRA + f];
}

__global__ __launch_bounds__(128) void mlp_k(const float* __restrict__ y0g,
                                             const float* __restrict__ lw1, const float* __restrict__ lb1,
                                             const float* __restrict__ lw2, const float* __restrict__ lb2,
                                             const float* __restrict__ lw3, const float* __restrict__ lb3,
                                             float* __restrict__ out) {
    __shared__ float y0s[272];
    __shared__ float y1s[128];
    int g = blockIdx.x, t = threadIdx.x;
    for (int i = t; i < 272; i += 128) y0s[i] = y0g[(size_t)g * 272 + i];
    __syncthreads();
    float acc = lb1[t];
    for (int k = 0; k < 272; k++) acc = fmaf(y0s[k], lw1[k * 128 + t], acc);
    y1s[t] = selu_f(acc);
    __syncthreads();
    if (t < 64) {
        float a2 = lb2[t];
        for (int k = 0; k < 128; k++) a2 = fmaf(y1s[k], lw2[k * 64 + t], a2);
        float v2 = selu_f(a2);
        float p = v2 * lw3[t];
#pragma unroll
        for (int off = 1; off < 64; off <<= 1) p += __shfl_xor(p, off, 64);
        if (t == 0) out[g] = p + lb3[0];
    }
}

extern "C" void kernel_launch(void* const* d_in, const int* in_sizes, int n_in,
                              void* d_out, int out_size, void* d_ws, size_t ws_size,
                              hipStream_t stream) {
    const int* src = (const int*)d_in[0];
    const int* dst = (const int*)d_in[1];
    const int* node_graph = (const int*)d_in[2];
    const float* feats_node = (const float*)d_in[3];
    const float* feats_graph = (const float*)d_in[4];
    const float* W1 = (const float*)d_in[5];
    const float* al1 = (const float*)d_in[6];
    const float* ar1 = (const float*)d_in[7];
    const float* bg1 = (const float*)d_in[8];
    const float* W2 = (const float*)d_in[9];
    const float* al2 = (const float*)d_in[10];
    const float* ar2 = (const float*)d_in[11];
    const float* bg2 = (const float*)d_in[12];
    const float* W3 = (const float*)d_in[13];
    const float* al3 = (const float*)d_in[14];
    const float* ar3 = (const float*)d_in[15];
    const float* bg3 = (const float*)d_in[16];
    const float* sw = (const float*)d_in[17];
    const float* sb = (const float*)d_in[18];
    const float* lw1 = (const float*)d_in[19];
    const float* lb1 = (const float*)d_in[20];
    const float* lw2 = (const float*)d_in[21];
    const float* lb2 = (const float*)d_in[22];
    const float* lw3 = (const float*)d_in[23];
    const float* lb3 = (const float*)d_in[24];
    float* out = (float*)d_out;

    char* ws = (char*)d_ws;
    size_t off = 0;
    auto alloc = [&](size_t bytes) -> char* {
        char* p = ws + off;
        off += (bytes + 255) & ~(size_t)255;
        return p;
    };
    float* bufA = (float*)alloc((size_t)N_NODES * HD * 4);   // h
    float* bufB = (float*)alloc((size_t)N_NODES * HD * 4);   // x
    float* el = (float*)alloc((size_t)N_NODES * 4 * 4);
    float* er = (float*)alloc((size_t)N_NODES * 4 * 4);
    float* wsc = (float*)alloc((size_t)N_NODES * 4);
    float* y0 = (float*)alloc((size_t)N_GRAPHS * 272 * 4);
    int* hist = (int*)alloc((size_t)N_NODES * 4);
    int* row_ptr = (int*)alloc((size_t)(N_NODES + 1) * 4);
    int* cursor = (int*)alloc((size_t)N_NODES * 4);
    int* edge_idx = (int*)alloc((size_t)N_EDGES * 4);
    int* gstart = (int*)alloc((size_t)(N_GRAPHS + 1) * 4);
    int* bsums = (int*)alloc(256 * 4);
    (void)ws_size; (void)in_sizes; (void)n_in; (void)out_size;

    hipMemsetAsync(hist, 0, (size_t)N_NODES * 4, stream);
    hipMemsetAsync(cursor, 0, (size_t)N_NODES * 4, stream);

    // CSR build (by dst)
    hist_k<<<(N_EDGES + 255) / 256, 256, 0, stream>>>(dst, hist);
    int nb = (N_NODES + SCAN_BLOCK - 1) / SCAN_BLOCK;  // 196
    scan1_k<<<nb, SCAN_BLOCK, 0, stream>>>(hist, row_ptr, bsums);
    scan2_k<<<1, 256, 0, stream>>>(bsums, nb);
    scan3_k<<<(N_NODES + 255) / 256, 256, 0, stream>>>(row_ptr, bsums);
    scatter_k<<<(N_EDGES + 255) / 256, 256, 0, stream>>>(dst, row_ptr, cursor, edge_idx);
    gbound_k<<<3, 256, 0, stream>>>(node_graph, gstart);

    dim3 ggrid(HD / 64, (N_NODES + 63) / 64);
    int nwb = (N_NODES + 3) / 4;  // wave-per-node blocks (4 waves/block)

    // layer 1
    gemm_k<64><<<ggrid, 256, 0, stream>>>(feats_node, W1, bufA, N_NODES);
    attn_logits_k<<<nwb, 256, 0, stream>>>(bufA, al1, ar1, el, er);
    gat_aggregate_k<<<nwb, 256, 0, stream>>>(bufA, el, er, src, row_ptr, edge_idx, bg1, bufB);
    // layer 2
    gemm_k<256><<<ggrid, 256, 0, stream>>>(bufB, W2, bufA, N_NODES);
    attn_logits_k<<<nwb, 256, 0, stream>>>(bufA, al2, ar2, el, er);
    gat_aggregate_k<<<nwb, 256, 0, stream>>>(bufA, el, er, src, row_ptr, edge_idx, bg2, bufB);
    // layer 3
    gemm_k<256><<<ggrid, 256, 0, stream>>>(bufB, W3, bufA, N_NODES);
    attn_logits_k<<<nwb, 256, 0, stream>>>(bufA, al3, ar3, el, er);
    gat_aggregate_k<<<nwb, 256, 0, stream>>>(bufA, el, er, src, row_ptr, edge_idx, bg3, bufB);

    // readout + MLP
    score_k<<<nwb, 256, 0, stream>>>(bufB, sw, sb, wsc);
    readout_k<<<N_GRAPHS, 256, 0, stream>>>(bufB, wsc, gstart, feats_graph, y0);
    mlp_k<<<N_GRAPHS, 128, 0, stream>>>(y0, lw1, lb1, lw2, lb2, lw3, lb3, out);
}

// Round 4
// 1181.554 us; speedup vs baseline: 1.5539x; 1.5539x over previous
//
#include <hip/hip_runtime.h>

#define N_NODES 100000
#define N_EDGES 1600000
#define N_GRAPHS 512
#define F_IN 64
#define HD 256
#define EXTRA 16
#define SCAN_BLOCK 512

typedef float f32x4 __attribute__((ext_vector_type(4)));
typedef _Float16 f16x4 __attribute__((ext_vector_type(4)));
typedef _Float16 f16x8 __attribute__((ext_vector_type(8)));

__device__ __forceinline__ float selu_f(float x) {
    const float a = 1.6732632423543772f, sc = 1.0507009873554805f;
    return x > 0.f ? sc * x : sc * a * (__expf(x) - 1.f);
}

// ---------------- CSR build ----------------
__global__ __launch_bounds__(256) void hist_k(const int* __restrict__ dst, int* __restrict__ hist) {
    int j = blockIdx.x * 256 + threadIdx.x;
    if (j < N_EDGES) atomicAdd(&hist[dst[j]], 1);
}

__global__ __launch_bounds__(SCAN_BLOCK) void scan1_k(const int* __restrict__ hist,
                                                      int* __restrict__ row_ptr,
                                                      int* __restrict__ bsums) {
    __shared__ int sm[SCAN_BLOCK];
    int t = threadIdx.x;
    int i = blockIdx.x * SCAN_BLOCK + t;
    int v = (i < N_NODES) ? hist[i] : 0;
    sm[t] = v;
    __syncthreads();
    for (int off = 1; off < SCAN_BLOCK; off <<= 1) {
        int add = (t >= off) ? sm[t - off] : 0;
        __syncthreads();
        sm[t] += add;
        __syncthreads();
    }
    if (i < N_NODES) row_ptr[i] = sm[t] - v;
    if (t == SCAN_BLOCK - 1) bsums[blockIdx.x] = sm[t];
}

__global__ __launch_bounds__(256) void scan2_k(int* __restrict__ bsums, int nb) {
    __shared__ int sm[256];
    int t = threadIdx.x;
    int v = (t < nb) ? bsums[t] : 0;
    sm[t] = v;
    __syncthreads();
    for (int off = 1; off < 256; off <<= 1) {
        int add = (t >= off) ? sm[t - off] : 0;
        __syncthreads();
        sm[t] += add;
        __syncthreads();
    }
    if (t < nb) bsums[t] = sm[t] - v;
}

__global__ __launch_bounds__(256) void scan3_k(int* __restrict__ row_ptr, const int* __restrict__ bsums) {
    int i = blockIdx.x * 256 + threadIdx.x;
    if (i < N_NODES) row_ptr[i] += bsums[i / SCAN_BLOCK];
    if (i == 0) row_ptr[N_NODES] = N_EDGES;
}

__global__ __launch_bounds__(256) void scatter_k(const int* __restrict__ dst,
                                                 const int* __restrict__ row_ptr,
                                                 int* __restrict__ cursor,
                                                 int* __restrict__ edge_idx) {
    int j = blockIdx.x * 256 + threadIdx.x;
    if (j < N_EDGES) {
        int d = dst[j];
        int r = atomicAdd(&cursor[d], 1);
        edge_idx[row_ptr[d] + r] = j;
    }
}

__global__ __launch_bounds__(256) void gbound_k(const int* __restrict__ node_graph, int* __restrict__ gstart) {
    int g = blockIdx.x * 256 + threadIdx.x;
    if (g > N_GRAPHS) return;
    int lo = 0, hi = N_NODES;
    while (lo < hi) {
        int mid = (lo + hi) >> 1;
        if (node_graph[mid] < g) lo = mid + 1; else hi = mid;
    }
    gstart[g] = lo;
}

// ---------------- weight split: W[k][n] fp32 -> Wt_hi/Wt_lo [n][k] f16 ----------------
__global__ __launch_bounds__(256) void tcast_split_k(const float* __restrict__ W,
                                                     _Float16* __restrict__ Wt_hi,
                                                     _Float16* __restrict__ Wt_lo, int K) {
    int idx = blockIdx.x * 256 + threadIdx.x;
    if (idx >= K * HD) return;
    int n = idx / K, k = idx - n * K;
    float w = W[(size_t)k * HD + n];
    _Float16 hi = (_Float16)w;
    _Float16 lo = (_Float16)(w - (float)hi);
    Wt_hi[idx] = hi;
    Wt_lo[idx] = lo;
}

// ---------------- split-f16 MFMA GEMM: C[M,256] = A[M,K](fp32) @ W[K,256] ----------------
// C written as hi/lo f16 pair (near-fp32 precision: hi*hi + hi*lo + lo*hi).
template <int K>
__global__ __launch_bounds__(256) void gemm_split_k(const float* __restrict__ A,
                                                    const _Float16* __restrict__ Bt_hi,
                                                    const _Float16* __restrict__ Bt_lo,
                                                    _Float16* __restrict__ Chi,
                                                    _Float16* __restrict__ Clo, int M) {
    const int BM = 128, BN = 128, LDP = 40;  // 40-f16 row pitch: 16B-aligned, 2-way-bank max
    __shared__ _Float16 As_hi[BM][LDP];
    __shared__ _Float16 As_lo[BM][LDP];
    __shared__ _Float16 Bs_hi[BN][LDP];
    __shared__ _Float16 Bs_lo[BN][LDP];
    int tid = threadIdx.x;
    int wave = tid >> 6, lane = tid & 63;
    int q = lane >> 4, l16 = lane & 15;
    int row0 = blockIdx.y * BM, col0 = blockIdx.x * BN;
    f32x4 acc[2][8] = {};

    for (int k0 = 0; k0 < K; k0 += 32) {
        // stage A (fp32 -> hi/lo f16): 128 rows x 32 floats, float4 chunks
#pragma unroll
        for (int c = 0; c < 4; c++) {
            int cc = tid + c * 256;
            int r = cc >> 3, o = (cc & 7) * 4;
            int gr = row0 + r;
            float4 v = make_float4(0.f, 0.f, 0.f, 0.f);
            if (gr < M) v = *(const float4*)(A + (size_t)gr * K + k0 + o);
            f16x4 hi, lo;
            hi.x = (_Float16)v.x; lo.x = (_Float16)(v.x - (float)hi.x);
            hi.y = (_Float16)v.y; lo.y = (_Float16)(v.y - (float)hi.y);
            hi.z = (_Float16)v.z; lo.z = (_Float16)(v.z - (float)hi.z);
            hi.w = (_Float16)v.w; lo.w = (_Float16)(v.w - (float)hi.w);
            *(f16x4*)&As_hi[r][o] = hi;
            *(f16x4*)&As_lo[r][o] = lo;
        }
        // stage B hi/lo: 128 n-rows x 32 f16 each, f16x8 chunks
#pragma unroll
        for (int c = 0; c < 2; c++) {
            int cc = tid + c * 256;
            int n = cc >> 2, o = (cc & 3) * 8;
            *(f16x8*)&Bs_hi[n][o] = *(const f16x8*)(Bt_hi + (size_t)(col0 + n) * K + k0 + o);
            *(f16x8*)&Bs_lo[n][o] = *(const f16x8*)(Bt_lo + (size_t)(col0 + n) * K + k0 + o);
        }
        __syncthreads();

        f16x8 ah[2], alo[2];
#pragma unroll
        for (int ms = 0; ms < 2; ms++) {
            int m = wave * 32 + ms * 16 + l16;
            ah[ms] = *(const f16x8*)&As_hi[m][q * 8];
            alo[ms] = *(const f16x8*)&As_lo[m][q * 8];
        }
#pragma unroll
        for (int ns = 0; ns < 8; ns++) {
            int n = ns * 16 + l16;
            f16x8 bh = *(const f16x8*)&Bs_hi[n][q * 8];
            f16x8 bl = *(const f16x8*)&Bs_lo[n][q * 8];
#pragma unroll
            for (int ms = 0; ms < 2; ms++) {
                acc[ms][ns] = __builtin_amdgcn_mfma_f32_16x16x32_f16(ah[ms], bh, acc[ms][ns], 0, 0, 0);
                acc[ms][ns] = __builtin_amdgcn_mfma_f32_16x16x32_f16(ah[ms], bl, acc[ms][ns], 0, 0, 0);
                acc[ms][ns] = __builtin_amdgcn_mfma_f32_16x16x32_f16(alo[ms], bh, acc[ms][ns], 0, 0, 0);
            }
        }
        __syncthreads();
    }
#pragma unroll
    for (int ms = 0; ms < 2; ms++) {
#pragma unroll
        for (int i = 0; i < 4; i++) {
            int r = row0 + wave * 32 + ms * 16 + q * 4 + i;
            if (r < M) {
#pragma unroll
                for (int ns = 0; ns < 8; ns++) {
                    float v = acc[ms][ns][i];
                    _Float16 hi = (_Float16)v;
                    _Float16 lo = (_Float16)(v - (float)hi);
                    Chi[(size_t)r * HD + col0 + ns * 16 + l16] = hi;
                    Clo[(size_t)r * HD + col0 + ns * 16 + l16] = lo;
                }
            }
        }
    }
}

// ---------------- per-node attention logits (exact h = hi+lo) ----------------
__global__ __launch_bounds__(256) void attn_logits_k(const _Float16* __restrict__ hhi,
                                                     const _Float16* __restrict__ hlo,
                                                     const float* __restrict__ al,
                                                     const float* __restrict__ ar,
                                                     float* __restrict__ el,
                                                     float* __restrict__ er) {
    int n = (blockIdx.x * 256 + threadIdx.x) / 64;
    int lane = threadIdx.x & 63;
    if (n >= N_NODES) return;
    f16x4 a = *(const f16x4*)(hhi + (size_t)n * HD + lane * 4);
    f16x4 b = *(const f16x4*)(hlo + (size_t)n * HD + lane * 4);
    float h0 = (float)a.x + (float)b.x, h1 = (float)a.y + (float)b.y;
    float h2 = (float)a.z + (float)b.z, h3 = (float)a.w + (float)b.w;
    float4 alv = *(const float4*)(al + lane * 4);
    float4 arv = *(const float4*)(ar + lane * 4);
    float pl = h0 * alv.x + h1 * alv.y + h2 * alv.z + h3 * alv.w;
    float pr = h0 * arv.x + h1 * arv.y + h2 * arv.z + h3 * arv.w;
#pragma unroll
    for (int off = 1; off < 16; off <<= 1) {
        pl += __shfl_xor(pl, off, 64);
        pr += __shfl_xor(pr, off, 64);
    }
    if ((lane & 15) == 0) {
        int head = lane >> 4;
        el[(size_t)n * 4 + head] = pl;
        er[(size_t)n * 4 + head] = pr;
    }
}

// ---------------- GAT aggregation: one wave per dst node; f16-hi messages, fp32 out ----------------
__global__ __launch_bounds__(256) void gat_aggregate_k(const _Float16* __restrict__ hb,
                                                       const float* __restrict__ el,
                                                       const float* __restrict__ er,
                                                       const int* __restrict__ src,
                                                       const int* __restrict__ row_ptr,
                                                       const int* __restrict__ edge_idx,
                                                       const float* __restrict__ bias,
                                                       float* __restrict__ xout) {
    int v = (blockIdx.x * 256 + threadIdx.x) / 64;
    int lane = threadIdx.x & 63;
    if (v >= N_NODES) return;
    int rs = row_ptr[v], re = row_ptr[v + 1];
    int deg = re - rs;
    float4 erv = *(const float4*)(er + (size_t)v * 4);

    float m[4] = {-1e30f, -1e30f, -1e30f, -1e30f};
    float s[4] = {0.f, 0.f, 0.f, 0.f};
    int my_sn = 0;
    float my_e[4] = {0.f, 0.f, 0.f, 0.f};
    for (int t = lane; t < deg; t += 64) {
        int j = edge_idx[rs + t];
        int sn = src[j];
        float4 elv = *(const float4*)(el + (size_t)sn * 4);
        float e[4];
        e[0] = elv.x + erv.x; e[1] = elv.y + erv.y; e[2] = elv.z + erv.z; e[3] = elv.w + erv.w;
#pragma unroll
        for (int hh = 0; hh < 4; hh++) {
            float ev = e[hh] > 0.f ? e[hh] : 0.2f * e[hh];
            e[hh] = ev;
            float mn = fmaxf(m[hh], ev);
            s[hh] = s[hh] * __expf(m[hh] - mn) + __expf(ev - mn);
            m[hh] = mn;
        }
        if (t == lane) {
            my_sn = sn;
            my_e[0] = e[0]; my_e[1] = e[1]; my_e[2] = e[2]; my_e[3] = e[3];
        }
    }
#pragma unroll
    for (int off = 32; off >= 1; off >>= 1) {
#pragma unroll
        for (int hh = 0; hh < 4; hh++) {
            float mo = __shfl_xor(m[hh], off, 64);
            float so = __shfl_xor(s[hh], off, 64);
            float mn = fmaxf(m[hh], mo);
            s[hh] = s[hh] * __expf(m[hh] - mn) + so * __expf(mo - mn);
            m[hh] = mn;
        }
    }

    int head = lane >> 4;
    float m_h = head == 0 ? m[0] : head == 1 ? m[1] : head == 2 ? m[2] : m[3];
    float den = head == 0 ? s[0] : head == 1 ? s[1] : head == 2 ? s[2] : s[3];
    float er_h = head == 0 ? erv.x : head == 1 ? erv.y : head == 2 ? erv.z : erv.w;
    float inv_den = 1.f / fmaxf(den, 1e-9f);

    float a0 = 0.f, a1 = 0.f, a2 = 0.f, a3 = 0.f;
    if (deg <= 64) {
        int t = 0;
        for (; t + 4 <= deg; t += 4) {
            int sn0, sn1, sn2, sn3;
            float w0, w1, w2, w3;
#pragma unroll
            for (int u = 0; u < 4; u++) {
                int sn = __shfl(my_sn, t + u, 64);
                float e0 = __shfl(my_e[0], t + u, 64);
                float e1 = __shfl(my_e[1], t + u, 64);
                float e2 = __shfl(my_e[2], t + u, 64);
                float e3 = __shfl(my_e[3], t + u, 64);
                float eh = head == 0 ? e0 : head == 1 ? e1 : head == 2 ? e2 : e3;
                float w = __expf(eh - m_h) * inv_den;
                if (u == 0) { sn0 = sn; w0 = w; }
                else if (u == 1) { sn1 = sn; w1 = w; }
                else if (u == 2) { sn2 = sn; w2 = w; }
                else { sn3 = sn; w3 = w; }
            }
            f16x4 hv0 = *(const f16x4*)(hb + (size_t)sn0 * HD + lane * 4);
            f16x4 hv1 = *(const f16x4*)(hb + (size_t)sn1 * HD + lane * 4);
            f16x4 hv2 = *(const f16x4*)(hb + (size_t)sn2 * HD + lane * 4);
            f16x4 hv3 = *(const f16x4*)(hb + (size_t)sn3 * HD + lane * 4);
            a0 = fmaf(w0, (float)hv0.x, a0); a1 = fmaf(w0, (float)hv0.y, a1);
            a2 = fmaf(w0, (float)hv0.z, a2); a3 = fmaf(w0, (float)hv0.w, a3);
            a0 = fmaf(w1, (float)hv1.x, a0); a1 = fmaf(w1, (float)hv1.y, a1);
            a2 = fmaf(w1, (float)hv1.z, a2); a3 = fmaf(w1, (float)hv1.w, a3);
            a0 = fmaf(w2, (float)hv2.x, a0); a1 = fmaf(w2, (float)hv2.y, a1);
            a2 = fmaf(w2, (float)hv2.z, a2); a3 = fmaf(w2, (float)hv2.w, a3);
            a0 = fmaf(w3, (float)hv3.x, a0); a1 = fmaf(w3, (float)hv3.y, a1);
            a2 = fmaf(w3, (float)hv3.z, a2); a3 = fmaf(w3, (float)hv3.w, a3);
        }
        for (; t < deg; t++) {
            int sn = __shfl(my_sn, t, 64);
            float e0 = __shfl(my_e[0], t, 64);
            float e1 = __shfl(my_e[1], t, 64);
            float e2 = __shfl(my_e[2], t, 64);
            float e3 = __shfl(my_e[3], t, 64);
            float eh = head == 0 ? e0 : head == 1 ? e1 : head == 2 ? e2 : e3;
            float w = __expf(eh - m_h) * inv_den;
            f16x4 hv = *(const f16x4*)(hb + (size_t)sn * HD + lane * 4);
            a0 = fmaf(w, (float)hv.x, a0); a1 = fmaf(w, (float)hv.y, a1);
            a2 = fmaf(w, (float)hv.z, a2); a3 = fmaf(w, (float)hv.w, a3);
        }
    } else {
        for (int t = 0; t < deg; t++) {
            int j = edge_idx[rs + t];
            int sn = src[j];
            float e = el[(size_t)sn * 4 + head] + er_h;
            e = e > 0.f ? e : 0.2f * e;
            float w = __expf(e - m_h) * inv_den;
            f16x4 hv = *(const f16x4*)(hb + (size_t)sn * HD + lane * 4);
            a0 = fmaf(w, (float)hv.x, a0); a1 = fmaf(w, (float)hv.y, a1);
            a2 = fmaf(w, (float)hv.z, a2); a3 = fmaf(w, (float)hv.w, a3);
        }
    }
    float4 bv = *(const float4*)(bias + lane * 4);
    float4 o;
    o.x = selu_f(a0 + bv.x);
    o.y = selu_f(a1 + bv.y);
    o.z = selu_f(a2 + bv.z);
    o.w = selu_f(a3 + bv.w);
    *(float4*)(xout + (size_t)v * HD + lane * 4) = o;
}

// ---------------- readout (fp32 x) ----------------
__global__ __launch_bounds__(256) void score_k(const float* __restrict__ x,
                                               const float* __restrict__ sw,
                                               const float* __restrict__ sb,
                                               float* __restrict__ wsc) {
    int n = (blockIdx.x * 256 + threadIdx.x) / 64;
    int lane = threadIdx.x & 63;
    if (n >= N_NODES) return;
    float4 xv = *(const float4*)(x + (size_t)n * HD + lane * 4);
    float4 sv = *(const float4*)(sw + lane * 4);
    float p = xv.x * sv.x + xv.y * sv.y + xv.z * sv.z + xv.w * sv.w;
#pragma unroll
    for (int off = 1; off < 64; off <<= 1) p += __shfl_xor(p, off, 64);
    if (lane == 0) wsc[n] = 1.f / (1.f + __expf(-(p + sb[0])));
}

__global__ __launch_bounds__(256) void readout_k(const float* __restrict__ x,
                                                 const float* __restrict__ wsc,
                                                 const int* __restrict__ gstart,
                                                 const float* __restrict__ fg,
                                                 float* __restrict__ y0) {
    int g = blockIdx.x;
    int f = threadIdx.x;
    int s = gstart[g], e = gstart[g + 1];
    float num = 0.f, den = 0.f;
    for (int n = s; n < e; n++) {
        float wn = wsc[n];
        num = fmaf(wn, x[(size_t)n * HD + f], num);
        den += wn;
    }
    float emb = num / fmaxf(den, 1e-9f);
    y0[(size_t)g * 272 + f] = emb;
    if (f < EXTRA) y0[(size_t)g * 272 + 256 + f] = fg[g * EXTRA + f];
}

__global__ __launch_bounds__(128) void mlp_k(const float* __restrict__ y0g,
                                             const float* __restrict__ lw1, const float* __restrict__ lb1,
                                             const float* __restrict__ lw2, const float* __restrict__ lb2,
                                             const float* __restrict__ lw3, const float* __restrict__ lb3,
                                             float* __restrict__ out) {
    __shared__ float y0s[272];
    __shared__ float y1s[128];
    int g = blockIdx.x, t = threadIdx.x;
    for (int i = t; i < 272; i += 128) y0s[i] = y0g[(size_t)g * 272 + i];
    __syncthreads();
    float acc = lb1[t];
    for (int k = 0; k < 272; k++) acc = fmaf(y0s[k], lw1[k * 128 + t], acc);
    y1s[t] = selu_f(acc);
    __syncthreads();
    if (t < 64) {
        float a2 = lb2[t];
        for (int k = 0; k < 128; k++) a2 = fmaf(y1s[k], lw2[k * 64 + t], a2);
        float v2 = selu_f(a2);
        float p = v2 * lw3[t];
#pragma unroll
        for (int off = 1; off < 64; off <<= 1) p += __shfl_xor(p, off, 64);
        if (t == 0) out[g] = p + lb3[0];
    }
}

extern "C" void kernel_launch(void* const* d_in, const int* in_sizes, int n_in,
                              void* d_out, int out_size, void* d_ws, size_t ws_size,
                              hipStream_t stream) {
    const int* src = (const int*)d_in[0];
    const int* dst = (const int*)d_in[1];
    const int* node_graph = (const int*)d_in[2];
    const float* feats_node = (const float*)d_in[3];
    const float* feats_graph = (const float*)d_in[4];
    const float* W1 = (const float*)d_in[5];
    const float* al1 = (const float*)d_in[6];
    const float* ar1 = (const float*)d_in[7];
    const float* bg1 = (const float*)d_in[8];
    const float* W2 = (const float*)d_in[9];
    const float* al2 = (const float*)d_in[10];
    const float* ar2 = (const float*)d_in[11];
    const float* bg2 = (const float*)d_in[12];
    const float* W3 = (const float*)d_in[13];
    const float* al3 = (const float*)d_in[14];
    const float* ar3 = (const float*)d_in[15];
    const float* bg3 = (const float*)d_in[16];
    const float* sw = (const float*)d_in[17];
    const float* sb = (const float*)d_in[18];
    const float* lw1 = (const float*)d_in[19];
    const float* lb1 = (const float*)d_in[20];
    const float* lw2 = (const float*)d_in[21];
    const float* lb2 = (const float*)d_in[22];
    const float* lw3 = (const float*)d_in[23];
    const float* lb3 = (const float*)d_in[24];
    float* out = (float*)d_out;

    char* ws = (char*)d_ws;
    size_t off = 0;
    auto alloc = [&](size_t bytes) -> char* {
        char* p = ws + off;
        off += (bytes + 255) & ~(size_t)255;
        return p;
    };
    float* xf32 = (float*)alloc((size_t)N_NODES * HD * 4);            // x (fp32)
    _Float16* hhi = (_Float16*)alloc((size_t)N_NODES * HD * 2);       // h hi (f16)
    _Float16* hlo = (_Float16*)alloc((size_t)N_NODES * HD * 2);       // h lo (f16)
    _Float16* W1hi = (_Float16*)alloc((size_t)F_IN * HD * 2);
    _Float16* W1lo = (_Float16*)alloc((size_t)F_IN * HD * 2);
    _Float16* W2hi = (_Float16*)alloc((size_t)HD * HD * 2);
    _Float16* W2lo = (_Float16*)alloc((size_t)HD * HD * 2);
    _Float16* W3hi = (_Float16*)alloc((size_t)HD * HD * 2);
    _Float16* W3lo = (_Float16*)alloc((size_t)HD * HD * 2);
    float* el = (float*)alloc((size_t)N_NODES * 4 * 4);
    float* er = (float*)alloc((size_t)N_NODES * 4 * 4);
    float* wsc = (float*)alloc((size_t)N_NODES * 4);
    float* y0 = (float*)alloc((size_t)N_GRAPHS * 272 * 4);
    int* hist = (int*)alloc((size_t)N_NODES * 4);
    int* row_ptr = (int*)alloc((size_t)(N_NODES + 1) * 4);
    int* cursor = (int*)alloc((size_t)N_NODES * 4);
    int* edge_idx = (int*)alloc((size_t)N_EDGES * 4);
    int* gstart = (int*)alloc((size_t)(N_GRAPHS + 1) * 4);
    int* bsums = (int*)alloc(256 * 4);
    (void)ws_size; (void)in_sizes; (void)n_in; (void)out_size;

    hipMemsetAsync(hist, 0, (size_t)N_NODES * 4, stream);
    hipMemsetAsync(cursor, 0, (size_t)N_NODES * 4, stream);

    // CSR build (by dst)
    hist_k<<<(N_EDGES + 255) / 256, 256, 0, stream>>>(dst, hist);
    int nb = (N_NODES + SCAN_BLOCK - 1) / SCAN_BLOCK;
    scan1_k<<<nb, SCAN_BLOCK, 0, stream>>>(hist, row_ptr, bsums);
    scan2_k<<<1, 256, 0, stream>>>(bsums, nb);
    scan3_k<<<(N_NODES + 255) / 256, 256, 0, stream>>>(row_ptr, bsums);
    scatter_k<<<(N_EDGES + 255) / 256, 256, 0, stream>>>(dst, row_ptr, cursor, edge_idx);
    gbound_k<<<3, 256, 0, stream>>>(node_graph, gstart);

    // weight splits
    tcast_split_k<<<(F_IN * HD + 255) / 256, 256, 0, stream>>>(W1, W1hi, W1lo, F_IN);
    tcast_split_k<<<(HD * HD + 255) / 256, 256, 0, stream>>>(W2, W2hi, W2lo, HD);
    tcast_split_k<<<(HD * HD + 255) / 256, 256, 0, stream>>>(W3, W3hi, W3lo, HD);

    dim3 ggrid(HD / 128, (N_NODES + 127) / 128);
    int nwb = (N_NODES + 3) / 4;

    // layer 1
    gemm_split_k<F_IN><<<ggrid, 256, 0, stream>>>(feats_node, W1hi, W1lo, hhi, hlo, N_NODES);
    attn_logits_k<<<nwb, 256, 0, stream>>>(hhi, hlo, al1, ar1, el, er);
    gat_aggregate_k<<<nwb, 256, 0, stream>>>(hhi, el, er, src, row_ptr, edge_idx, bg1, xf32);
    // layer 2
    gemm_split_k<HD><<<ggrid, 256, 0, stream>>>(xf32, W2hi, W2lo, hhi, hlo, N_NODES);
    attn_logits_k<<<nwb, 256, 0, stream>>>(hhi, hlo, al2, ar2, el, er);
    gat_aggregate_k<<<nwb, 256, 0, stream>>>(hhi, el, er, src, row_ptr, edge_idx, bg2, xf32);
    // layer 3
    gemm_split_k<HD><<<ggrid, 256, 0, stream>>>(xf32, W3hi, W3lo, hhi, hlo, N_NODES);
    attn_logits_k<<<nwb, 256, 0, stream>>>(hhi, hlo, al3, ar3, el, er);
    gat_aggregate_k<<<nwb, 256, 0, stream>>>(hhi, el, er, src, row_ptr, edge_idx, bg3, xf32);

    // readout + MLP
    score_k<<<nwb, 256, 0, stream>>>(xf32, sw, sb, wsc);
    readout_k<<<N_GRAPHS, 256, 0, stream>>>(xf32, wsc, gstart, feats_graph, y0);
    mlp_k<<<N_GRAPHS, 128, 0, stream>>>(y0, lw1, lb1, lw2, lb2, lw3, lb3, out);
}

// Round 5
// 1011.875 us; speedup vs baseline: 1.8145x; 1.1677x over previous
//
#include <hip/hip_runtime.h>

#define N_NODES 100000
#define N_EDGES 1600000
#define N_GRAPHS 512
#define F_IN 64
#define HD 256
#define EXTRA 16
#define SCAN_BLOCK 512

typedef float f32x4 __attribute__((ext_vector_type(4)));
typedef _Float16 f16x4 __attribute__((ext_vector_type(4)));
typedef _Float16 f16x8 __attribute__((ext_vector_type(8)));

__device__ __forceinline__ float selu_f(float x) {
    const float a = 1.6732632423543772f, sc = 1.0507009873554805f;
    return x > 0.f ? sc * x : sc * a * (__expf(x) - 1.f);
}

// ---------------- CSR build ----------------
__global__ __launch_bounds__(256) void hist_k(const int* __restrict__ dst, int* __restrict__ hist) {
    int j = blockIdx.x * 256 + threadIdx.x;
    if (j < N_EDGES) atomicAdd(&hist[dst[j]], 1);
}

__global__ __launch_bounds__(SCAN_BLOCK) void scan1_k(const int* __restrict__ hist,
                                                      int* __restrict__ row_ptr,
                                                      int* __restrict__ bsums) {
    __shared__ int sm[SCAN_BLOCK];
    int t = threadIdx.x;
    int i = blockIdx.x * SCAN_BLOCK + t;
    int v = (i < N_NODES) ? hist[i] : 0;
    sm[t] = v;
    __syncthreads();
    for (int off = 1; off < SCAN_BLOCK; off <<= 1) {
        int add = (t >= off) ? sm[t - off] : 0;
        __syncthreads();
        sm[t] += add;
        __syncthreads();
    }
    if (i < N_NODES) row_ptr[i] = sm[t] - v;
    if (t == SCAN_BLOCK - 1) bsums[blockIdx.x] = sm[t];
}

__global__ __launch_bounds__(256) void scan2_k(int* __restrict__ bsums, int nb) {
    __shared__ int sm[256];
    int t = threadIdx.x;
    int v = (t < nb) ? bsums[t] : 0;
    sm[t] = v;
    __syncthreads();
    for (int off = 1; off < 256; off <<= 1) {
        int add = (t >= off) ? sm[t - off] : 0;
        __syncthreads();
        sm[t] += add;
        __syncthreads();
    }
    if (t < nb) bsums[t] = sm[t] - v;
}

__global__ __launch_bounds__(256) void scan3_k(int* __restrict__ row_ptr, const int* __restrict__ bsums) {
    int i = blockIdx.x * 256 + threadIdx.x;
    if (i < N_NODES) row_ptr[i] += bsums[i / SCAN_BLOCK];
    if (i == 0) row_ptr[N_NODES] = N_EDGES;
}

// stores src node id in CSR order (no edge_idx indirection needed later)
__global__ __launch_bounds__(256) void scatter_k(const int* __restrict__ src,
                                                 const int* __restrict__ dst,
                                                 const int* __restrict__ row_ptr,
                                                 int* __restrict__ cursor,
                                                 int* __restrict__ csr_src) {
    int j = blockIdx.x * 256 + threadIdx.x;
    if (j < N_EDGES) {
        int d = dst[j];
        int r = atomicAdd(&cursor[d], 1);
        csr_src[row_ptr[d] + r] = src[j];
    }
}

__global__ __launch_bounds__(256) void gbound_k(const int* __restrict__ node_graph, int* __restrict__ gstart) {
    int g = blockIdx.x * 256 + threadIdx.x;
    if (g > N_GRAPHS) return;
    int lo = 0, hi = N_NODES;
    while (lo < hi) {
        int mid = (lo + hi) >> 1;
        if (node_graph[mid] < g) lo = mid + 1; else hi = mid;
    }
    gstart[g] = lo;
}

// ---------------- weight split: W[k][n] fp32 -> Wt_hi/Wt_lo [n][k] f16 ----------------
__global__ __launch_bounds__(256) void tcast_split_k(const float* __restrict__ W,
                                                     _Float16* __restrict__ Wt_hi,
                                                     _Float16* __restrict__ Wt_lo, int K) {
    int idx = blockIdx.x * 256 + threadIdx.x;
    if (idx >= K * HD) return;
    int n = idx / K, k = idx - n * K;
    float w = W[(size_t)k * HD + n];
    _Float16 hi = (_Float16)w;
    _Float16 lo = (_Float16)(w - (float)hi);
    Wt_hi[idx] = hi;
    Wt_lo[idx] = lo;
}

// ---------------- split-f16 MFMA GEMM + fused attn-logit epilogue ----------------
// C[M,256] = A[M,K](fp32) @ W[K,256]; h stored f16(hi); el/er computed from fp32 acc.
// Each 128-col block owns heads h0=col0/64 and h0+1 -> writes disjoint el/er entries.
template <int K>
__global__ __launch_bounds__(256) void gemm_split_k(const float* __restrict__ A,
                                                    const _Float16* __restrict__ Bt_hi,
                                                    const _Float16* __restrict__ Bt_lo,
                                                    const float* __restrict__ al,
                                                    const float* __restrict__ ar,
                                                    _Float16* __restrict__ Chi,
                                                    float* __restrict__ el,
                                                    float* __restrict__ er, int M) {
    const int BM = 128, BN = 128, LDP = 40;
    __shared__ _Float16 As_hi[BM][LDP];
    __shared__ _Float16 As_lo[BM][LDP];
    __shared__ _Float16 Bs_hi[BN][LDP];
    __shared__ _Float16 Bs_lo[BN][LDP];
    int tid = threadIdx.x;
    int wave = tid >> 6, lane = tid & 63;
    int q = lane >> 4, l16 = lane & 15;
    int row0 = blockIdx.y * BM, col0 = blockIdx.x * BN;
    f32x4 acc[2][8] = {};

    for (int k0 = 0; k0 < K; k0 += 32) {
#pragma unroll
        for (int c = 0; c < 4; c++) {
            int cc = tid + c * 256;
            int r = cc >> 3, o = (cc & 7) * 4;
            int gr = row0 + r;
            float4 v = make_float4(0.f, 0.f, 0.f, 0.f);
            if (gr < M) v = *(const float4*)(A + (size_t)gr * K + k0 + o);
            f16x4 hi, lo;
            hi.x = (_Float16)v.x; lo.x = (_Float16)(v.x - (float)hi.x);
            hi.y = (_Float16)v.y; lo.y = (_Float16)(v.y - (float)hi.y);
            hi.z = (_Float16)v.z; lo.z = (_Float16)(v.z - (float)hi.z);
            hi.w = (_Float16)v.w; lo.w = (_Float16)(v.w - (float)hi.w);
            *(f16x4*)&As_hi[r][o] = hi;
            *(f16x4*)&As_lo[r][o] = lo;
        }
#pragma unroll
        for (int c = 0; c < 2; c++) {
            int cc = tid + c * 256;
            int n = cc >> 2, o = (cc & 3) * 8;
            *(f16x8*)&Bs_hi[n][o] = *(const f16x8*)(Bt_hi + (size_t)(col0 + n) * K + k0 + o);
            *(f16x8*)&Bs_lo[n][o] = *(const f16x8*)(Bt_lo + (size_t)(col0 + n) * K + k0 + o);
        }
        __syncthreads();

        f16x8 ah[2], alo2[2];
#pragma unroll
        for (int ms = 0; ms < 2; ms++) {
            int m = wave * 32 + ms * 16 + l16;
            ah[ms] = *(const f16x8*)&As_hi[m][q * 8];
            alo2[ms] = *(const f16x8*)&As_lo[m][q * 8];
        }
#pragma unroll
        for (int ns = 0; ns < 8; ns++) {
            int n = ns * 16 + l16;
            f16x8 bh = *(const f16x8*)&Bs_hi[n][q * 8];
            f16x8 bl = *(const f16x8*)&Bs_lo[n][q * 8];
#pragma unroll
            for (int ms = 0; ms < 2; ms++) {
                acc[ms][ns] = __builtin_amdgcn_mfma_f32_16x16x32_f16(ah[ms], bh, acc[ms][ns], 0, 0, 0);
                acc[ms][ns] = __builtin_amdgcn_mfma_f32_16x16x32_f16(ah[ms], bl, acc[ms][ns], 0, 0, 0);
                acc[ms][ns] = __builtin_amdgcn_mfma_f32_16x16x32_f16(alo2[ms], bh, acc[ms][ns], 0, 0, 0);
            }
        }
        __syncthreads();
    }

    // fused epilogue: store h (f16 hi) + per-head logit dot products from fp32 acc
    const int h0 = col0 >> 6;  // this block covers heads h0, h0+1
    float alv[8], arv[8];
#pragma unroll
    for (int ns = 0; ns < 8; ns++) {
        int hh = h0 + (ns >> 2);
        int d = (ns & 3) * 16 + l16;
        alv[ns] = al[hh * 64 + d];
        arv[ns] = ar[hh * 64 + d];
    }
#pragma unroll
    for (int ms = 0; ms < 2; ms++) {
#pragma unroll
        for (int i = 0; i < 4; i++) {
            int r = row0 + wave * 32 + ms * 16 + q * 4 + i;
            bool ok = r < M;
            float el0 = 0.f, er0 = 0.f, el1 = 0.f, er1 = 0.f;
#pragma unroll
            for (int ns = 0; ns < 8; ns++) {
                float v = acc[ms][ns][i];
                if (ok) Chi[(size_t)r * HD + col0 + ns * 16 + l16] = (_Float16)v;
                if (ns < 4) { el0 = fmaf(v, alv[ns], el0); er0 = fmaf(v, arv[ns], er0); }
                else        { el1 = fmaf(v, alv[ns], el1); er1 = fmaf(v, arv[ns], er1); }
            }
#pragma unroll
            for (int off = 1; off < 16; off <<= 1) {
                el0 += __shfl_xor(el0, off, 64);
                er0 += __shfl_xor(er0, off, 64);
                el1 += __shfl_xor(el1, off, 64);
                er1 += __shfl_xor(er1, off, 64);
            }
            if (l16 == 0 && ok) {
                el[(size_t)r * 4 + h0] = el0;
                el[(size_t)r * 4 + h0 + 1] = el1;
                er[(size_t)r * 4 + h0] = er0;
                er[(size_t)r * 4 + h0 + 1] = er1;
            }
        }
    }
}

// ---------------- GAT aggregation: wave per dst node, LDS-cached edge weights ----------------
__global__ __launch_bounds__(256) void gat_aggregate_k(const _Float16* __restrict__ hb,
                                                       const float* __restrict__ el,
                                                       const float* __restrict__ er,
                                                       const int* __restrict__ csr_src,
                                                       const int* __restrict__ row_ptr,
                                                       const float* __restrict__ bias,
                                                       float* __restrict__ xout) {
    __shared__ float wlds[4][64][4];  // [wave][edge][head]
    __shared__ int snlds[4][64];
    int wv = threadIdx.x >> 6;
    int lane = threadIdx.x & 63;
    int v = blockIdx.x * 4 + wv;
    bool valid = v < N_NODES;
    int vc = valid ? v : 0;
    int rs = row_ptr[vc];
    int deg = valid ? row_ptr[vc + 1] - rs : 0;
    float4 erv = make_float4(0.f, 0.f, 0.f, 0.f);
    if (valid) erv = *(const float4*)(er + (size_t)vc * 4);

    float m[4] = {-1e30f, -1e30f, -1e30f, -1e30f};
    float s[4] = {0.f, 0.f, 0.f, 0.f};
    float m_h = 0.f, inv_den = 1.f, er_h = 0.f;
    int head = lane >> 4;

    if (deg <= 64) {
        int my_sn = 0;
        float my_e[4] = {0.f, 0.f, 0.f, 0.f};
        if (lane < deg) {
            int sn = csr_src[rs + lane];
            my_sn = sn;
            float4 elv = *(const float4*)(el + (size_t)sn * 4);
            float e0 = elv.x + erv.x, e1 = elv.y + erv.y, e2 = elv.z + erv.z, e3 = elv.w + erv.w;
            my_e[0] = e0 > 0.f ? e0 : 0.2f * e0;
            my_e[1] = e1 > 0.f ? e1 : 0.2f * e1;
            my_e[2] = e2 > 0.f ? e2 : 0.2f * e2;
            my_e[3] = e3 > 0.f ? e3 : 0.2f * e3;
#pragma unroll
            for (int hh = 0; hh < 4; hh++) { m[hh] = my_e[hh]; s[hh] = 1.f; }
        }
        for (int off = 1; off < deg && off < 64; off <<= 1) {
#pragma unroll
            for (int hh = 0; hh < 4; hh++) {
                float mo = __shfl_xor(m[hh], off, 64);
                float so = __shfl_xor(s[hh], off, 64);
                float mn = fmaxf(m[hh], mo);
                s[hh] = s[hh] * __expf(m[hh] - mn) + so * __expf(mo - mn);
                m[hh] = mn;
            }
        }
        if (lane < deg) {
#pragma unroll
            for (int hh = 0; hh < 4; hh++)
                wlds[wv][lane][hh] = __expf(my_e[hh] - m[hh]) / fmaxf(s[hh], 1e-9f);
            snlds[wv][lane] = my_sn;
        }
    } else {
        // slow path (deg > 64): online softmax over strided edges, full reduce
        for (int t = lane; t < deg; t += 64) {
            int sn = csr_src[rs + t];
            float4 elv = *(const float4*)(el + (size_t)sn * 4);
            float e[4];
            e[0] = elv.x + erv.x; e[1] = elv.y + erv.y; e[2] = elv.z + erv.z; e[3] = elv.w + erv.w;
#pragma unroll
            for (int hh = 0; hh < 4; hh++) {
                float ev = e[hh] > 0.f ? e[hh] : 0.2f * e[hh];
                float mn = fmaxf(m[hh], ev);
                s[hh] = s[hh] * __expf(m[hh] - mn) + __expf(ev - mn);
                m[hh] = mn;
            }
        }
#pragma unroll
        for (int off = 32; off >= 1; off >>= 1) {
#pragma unroll
            for (int hh = 0; hh < 4; hh++) {
                float mo = __shfl_xor(m[hh], off, 64);
                float so = __shfl_xor(s[hh], off, 64);
                float mn = fmaxf(m[hh], mo);
                s[hh] = s[hh] * __expf(m[hh] - mn) + so * __expf(mo - mn);
                m[hh] = mn;
            }
        }
        m_h = head == 0 ? m[0] : head == 1 ? m[1] : head == 2 ? m[2] : m[3];
        float den = head == 0 ? s[0] : head == 1 ? s[1] : head == 2 ? s[2] : s[3];
        er_h = head == 0 ? erv.x : head == 1 ? erv.y : head == 2 ? erv.z : erv.w;
        inv_den = 1.f / fmaxf(den, 1e-9f);
    }
    __syncthreads();

    float a0 = 0.f, a1 = 0.f, a2 = 0.f, a3 = 0.f;
    if (deg <= 64) {
        int t = 0;
        for (; t + 8 <= deg; t += 8) {
            int sn[8];
            float w[8];
#pragma unroll
            for (int u = 0; u < 8; u++) {
                sn[u] = snlds[wv][t + u];
                w[u] = wlds[wv][t + u][head];
            }
            f16x4 hv[8];
#pragma unroll
            for (int u = 0; u < 8; u++)
                hv[u] = *(const f16x4*)(hb + (size_t)sn[u] * HD + lane * 4);
#pragma unroll
            for (int u = 0; u < 8; u++) {
                a0 = fmaf(w[u], (float)hv[u].x, a0);
                a1 = fmaf(w[u], (float)hv[u].y, a1);
                a2 = fmaf(w[u], (float)hv[u].z, a2);
                a3 = fmaf(w[u], (float)hv[u].w, a3);
            }
        }
        for (; t < deg; t++) {
            int sn = snlds[wv][t];
            float w = wlds[wv][t][head];
            f16x4 hv = *(const f16x4*)(hb + (size_t)sn * HD + lane * 4);
            a0 = fmaf(w, (float)hv.x, a0);
            a1 = fmaf(w, (float)hv.y, a1);
            a2 = fmaf(w, (float)hv.z, a2);
            a3 = fmaf(w, (float)hv.w, a3);
        }
    } else {
        for (int t = 0; t < deg; t++) {
            int sn = csr_src[rs + t];
            float e = el[(size_t)sn * 4 + head] + er_h;
            e = e > 0.f ? e : 0.2f * e;
            float w = __expf(e - m_h) * inv_den;
            f16x4 hv = *(const f16x4*)(hb + (size_t)sn * HD + lane * 4);
            a0 = fmaf(w, (float)hv.x, a0);
            a1 = fmaf(w, (float)hv.y, a1);
            a2 = fmaf(w, (float)hv.z, a2);
            a3 = fmaf(w, (float)hv.w, a3);
        }
    }
    if (valid) {
        float4 bv = *(const float4*)(bias + lane * 4);
        float4 o;
        o.x = selu_f(a0 + bv.x);
        o.y = selu_f(a1 + bv.y);
        o.z = selu_f(a2 + bv.z);
        o.w = selu_f(a3 + bv.w);
        *(float4*)(xout + (size_t)v * HD + lane * 4) = o;
    }
}

// ---------------- readout (fp32 x) ----------------
__global__ __launch_bounds__(256) void score_k(const float* __restrict__ x,
                                               const float* __restrict__ sw,
                                               const float* __restrict__ sb,
                                               float* __restrict__ wsc) {
    int n = (blockIdx.x * 256 + threadIdx.x) / 64;
    int lane = threadIdx.x & 63;
    if (n >= N_NODES) return;
    float4 xv = *(const float4*)(x + (size_t)n * HD + lane * 4);
    float4 sv = *(const float4*)(sw + lane * 4);
    float p = xv.x * sv.x + xv.y * sv.y + xv.z * sv.z + xv.w * sv.w;
#pragma unroll
    for (int off = 1; off < 64; off <<= 1) p += __shfl_xor(p, off, 64);
    if (lane == 0) wsc[n] = 1.f / (1.f + __expf(-(p + sb[0])));
}

__global__ __launch_bounds__(256) void readout_k(const float* __restrict__ x,
                                                 const float* __restrict__ wsc,
                                                 const int* __restrict__ gstart,
                                                 const float* __restrict__ fg,
                                                 float* __restrict__ y0) {
    int g = blockIdx.x;
    int f = threadIdx.x;
    int s = gstart[g], e = gstart[g + 1];
    float num = 0.f, den = 0.f;
    for (int n = s; n < e; n++) {
        float wn = wsc[n];
        num = fmaf(wn, x[(size_t)n * HD + f], num);
        den += wn;
    }
    float emb = num / fmaxf(den, 1e-9f);
    y0[(size_t)g * 272 + f] = emb;
    if (f < EXTRA) y0[(size_t)g * 272 + 256 + f] = fg[g * EXTRA + f];
}

__global__ __launch_bounds__(128) void mlp_k(const float* __restrict__ y0g,
                                             const float* __restrict__ lw1, const float* __restrict__ lb1,
                                             const float* __restrict__ lw2, const float* __restrict__ lb2,
                                             const float* __restrict__ lw3, const float* __restrict__ lb3,
                                             float* __restrict__ out) {
    __shared__ float y0s[272];
    __shared__ float y1s[128];
    int g = blockIdx.x, t = threadIdx.x;
    for (int i = t; i < 272; i += 128) y0s[i] = y0g[(size_t)g * 272 + i];
    __syncthreads();
    float acc = lb1[t];
    for (int k = 0; k < 272; k++) acc = fmaf(y0s[k], lw1[k * 128 + t], acc);
    y1s[t] = selu_f(acc);
    __syncthreads();
    if (t < 64) {
        float a2 = lb2[t];
        for (int k = 0; k < 128; k++) a2 = fmaf(y1s[k], lw2[k * 64 + t], a2);
        float v2 = selu_f(a2);
        float p = v2 * lw3[t];
#pragma unroll
        for (int off = 1; off < 64; off <<= 1) p += __shfl_xor(p, off, 64);
        if (t == 0) out[g] = p + lb3[0];
    }
}

extern "C" void kernel_launch(void* const* d_in, const int* in_sizes, int n_in,
                              void* d_out, int out_size, void* d_ws, size_t ws_size,
                              hipStream_t stream) {
    const int* src = (const int*)d_in[0];
    const int* dst = (const int*)d_in[1];
    const int* node_graph = (const int*)d_in[2];
    const float* feats_node = (const float*)d_in[3];
    const float* feats_graph = (const float*)d_in[4];
    const float* W1 = (const float*)d_in[5];
    const float* al1 = (const float*)d_in[6];
    const float* ar1 = (const float*)d_in[7];
    const float* bg1 = (const float*)d_in[8];
    const float* W2 = (const float*)d_in[9];
    const float* al2 = (const float*)d_in[10];
    const float* ar2 = (const float*)d_in[11];
    const float* bg2 = (const float*)d_in[12];
    const float* W3 = (const float*)d_in[13];
    const float* al3 = (const float*)d_in[14];
    const float* ar3 = (const float*)d_in[15];
    const float* bg3 = (const float*)d_in[16];
    const float* sw = (const float*)d_in[17];
    const float* sb = (const float*)d_in[18];
    const float* lw1 = (const float*)d_in[19];
    const float* lb1 = (const float*)d_in[20];
    const float* lw2 = (const float*)d_in[21];
    const float* lb2 = (const float*)d_in[22];
    const float* lw3 = (const float*)d_in[23];
    const float* lb3 = (const float*)d_in[24];
    float* out = (float*)d_out;

    char* ws = (char*)d_ws;
    size_t off = 0;
    auto alloc = [&](size_t bytes) -> char* {
        char* p = ws + off;
        off += (bytes + 255) & ~(size_t)255;
        return p;
    };
    float* xf32 = (float*)alloc((size_t)N_NODES * HD * 4);            // x (fp32)
    _Float16* hhi = (_Float16*)alloc((size_t)N_NODES * HD * 2);       // h (f16 hi)
    _Float16* W1hi = (_Float16*)alloc((size_t)F_IN * HD * 2);
    _Float16* W1lo = (_Float16*)alloc((size_t)F_IN * HD * 2);
    _Float16* W2hi = (_Float16*)alloc((size_t)HD * HD * 2);
    _Float16* W2lo = (_Float16*)alloc((size_t)HD * HD * 2);
    _Float16* W3hi = (_Float16*)alloc((size_t)HD * HD * 2);
    _Float16* W3lo = (_Float16*)alloc((size_t)HD * HD * 2);
    float* el = (float*)alloc((size_t)N_NODES * 4 * 4);
    float* er = (float*)alloc((size_t)N_NODES * 4 * 4);
    float* wsc = (float*)alloc((size_t)N_NODES * 4);
    float* y0 = (float*)alloc((size_t)N_GRAPHS * 272 * 4);
    int* hist = (int*)alloc((size_t)N_NODES * 4);
    int* row_ptr = (int*)alloc((size_t)(N_NODES + 1) * 4);
    int* cursor = (int*)alloc((size_t)N_NODES * 4);
    int* csr_src = (int*)alloc((size_t)N_EDGES * 4);
    int* gstart = (int*)alloc((size_t)(N_GRAPHS + 1) * 4);
    int* bsums = (int*)alloc(256 * 4);
    (void)ws_size; (void)in_sizes; (void)n_in; (void)out_size;

    hipMemsetAsync(hist, 0, (size_t)N_NODES * 4, stream);
    hipMemsetAsync(cursor, 0, (size_t)N_NODES * 4, stream);

    // CSR build (by dst)
    hist_k<<<(N_EDGES + 255) / 256, 256, 0, stream>>>(dst, hist);
    int nb = (N_NODES + SCAN_BLOCK - 1) / SCAN_BLOCK;
    scan1_k<<<nb, SCAN_BLOCK, 0, stream>>>(hist, row_ptr, bsums);
    scan2_k<<<1, 256, 0, stream>>>(bsums, nb);
    scan3_k<<<(N_NODES + 255) / 256, 256, 0, stream>>>(row_ptr, bsums);
    scatter_k<<<(N_EDGES + 255) / 256, 256, 0, stream>>>(src, dst, row_ptr, cursor, csr_src);
    gbound_k<<<3, 256, 0, stream>>>(node_graph, gstart);

    // weight splits
    tcast_split_k<<<(F_IN * HD + 255) / 256, 256, 0, stream>>>(W1, W1hi, W1lo, F_IN);
    tcast_split_k<<<(HD * HD + 255) / 256, 256, 0, stream>>>(W2, W2hi, W2lo, HD);
    tcast_split_k<<<(HD * HD + 255) / 256, 256, 0, stream>>>(W3, W3hi, W3lo, HD);

    dim3 ggrid(HD / 128, (N_NODES + 127) / 128);
    int nwb = (N_NODES + 3) / 4;

    // layer 1
    gemm_split_k<F_IN><<<ggrid, 256, 0, stream>>>(feats_node, W1hi, W1lo, al1, ar1, hhi, el, er, N_NODES);
    gat_aggregate_k<<<nwb, 256, 0, stream>>>(hhi, el, er, csr_src, row_ptr, bg1, xf32);
    // layer 2
    gemm_split_k<HD><<<ggrid, 256, 0, stream>>>(xf32, W2hi, W2lo, al2, ar2, hhi, el, er, N_NODES);
    gat_aggregate_k<<<nwb, 256, 0, stream>>>(hhi, el, er, csr_src, row_ptr, bg2, xf32);
    // layer 3
    gemm_split_k<HD><<<ggrid, 256, 0, stream>>>(xf32, W3hi, W3lo, al3, ar3, hhi, el, er, N_NODES);
    gat_aggregate_k<<<nwb, 256, 0, stream>>>(hhi, el, er, csr_src, row_ptr, bg3, xf32);

    // readout + MLP
    score_k<<<nwb, 256, 0, stream>>>(xf32, sw, sb, wsc);
    readout_k<<<N_GRAPHS, 256, 0, stream>>>(xf32, wsc, gstart, feats_graph, y0);
    mlp_k<<<N_GRAPHS, 128, 0, stream>>>(y0, lw1, lb1, lw2, lb2, lw3, lb3, out);
}

// Round 6
// 973.003 us; speedup vs baseline: 1.8870x; 1.0400x over previous
//
#include <hip/hip_runtime.h>

#define N_NODES 100000
#define N_EDGES 1600000
#define N_GRAPHS 512
#define F_IN 64
#define HD 256
#define EXTRA 16
#define SCAN_BLOCK 512

typedef float f32x4 __attribute__((ext_vector_type(4)));
typedef _Float16 f16x4 __attribute__((ext_vector_type(4)));
typedef _Float16 f16x8 __attribute__((ext_vector_type(8)));

__device__ __forceinline__ float selu_f(float x) {
    const float a = 1.6732632423543772f, sc = 1.0507009873554805f;
    return x > 0.f ? sc * x : sc * a * (__expf(x) - 1.f);
}

// ---------------- CSR build ----------------
__global__ __launch_bounds__(256) void hist_k(const int* __restrict__ dst, int* __restrict__ hist) {
    int j = blockIdx.x * 256 + threadIdx.x;
    if (j < N_EDGES) atomicAdd(&hist[dst[j]], 1);
}

__global__ __launch_bounds__(SCAN_BLOCK) void scan1_k(const int* __restrict__ hist,
                                                      int* __restrict__ row_ptr,
                                                      int* __restrict__ bsums) {
    __shared__ int sm[SCAN_BLOCK];
    int t = threadIdx.x;
    int i = blockIdx.x * SCAN_BLOCK + t;
    int v = (i < N_NODES) ? hist[i] : 0;
    sm[t] = v;
    __syncthreads();
    for (int off = 1; off < SCAN_BLOCK; off <<= 1) {
        int add = (t >= off) ? sm[t - off] : 0;
        __syncthreads();
        sm[t] += add;
        __syncthreads();
    }
    if (i < N_NODES) row_ptr[i] = sm[t] - v;
    if (t == SCAN_BLOCK - 1) bsums[blockIdx.x] = sm[t];
}

__global__ __launch_bounds__(256) void scan2_k(int* __restrict__ bsums, int nb) {
    __shared__ int sm[256];
    int t = threadIdx.x;
    int v = (t < nb) ? bsums[t] : 0;
    sm[t] = v;
    __syncthreads();
    for (int off = 1; off < 256; off <<= 1) {
        int add = (t >= off) ? sm[t - off] : 0;
        __syncthreads();
        sm[t] += add;
        __syncthreads();
    }
    if (t < nb) bsums[t] = sm[t] - v;
}

__global__ __launch_bounds__(256) void scan3_k(int* __restrict__ row_ptr, const int* __restrict__ bsums) {
    int i = blockIdx.x * 256 + threadIdx.x;
    if (i < N_NODES) row_ptr[i] += bsums[i / SCAN_BLOCK];
    if (i == 0) row_ptr[N_NODES] = N_EDGES;
}

__global__ __launch_bounds__(256) void scatter_k(const int* __restrict__ src,
                                                 const int* __restrict__ dst,
                                                 const int* __restrict__ row_ptr,
                                                 int* __restrict__ cursor,
                                                 int* __restrict__ csr_src) {
    int j = blockIdx.x * 256 + threadIdx.x;
    if (j < N_EDGES) {
        int d = dst[j];
        int r = atomicAdd(&cursor[d], 1);
        csr_src[row_ptr[d] + r] = src[j];
    }
}

__global__ __launch_bounds__(256) void gbound_k(const int* __restrict__ node_graph, int* __restrict__ gstart) {
    int g = blockIdx.x * 256 + threadIdx.x;
    if (g > N_GRAPHS) return;
    int lo = 0, hi = N_NODES;
    while (lo < hi) {
        int mid = (lo + hi) >> 1;
        if (node_graph[mid] < g) lo = mid + 1; else hi = mid;
    }
    gstart[g] = lo;
}

// ---------------- weight split: W[k][n] fp32 -> Wt_hi/Wt_lo [n][k] f16 ----------------
__global__ __launch_bounds__(256) void tcast_split_k(const float* __restrict__ W,
                                                     _Float16* __restrict__ Wt_hi,
                                                     _Float16* __restrict__ Wt_lo, int K) {
    int idx = blockIdx.x * 256 + threadIdx.x;
    if (idx >= K * HD) return;
    int n = idx / K, k = idx - n * K;
    float w = W[(size_t)k * HD + n];
    _Float16 hi = (_Float16)w;
    _Float16 lo = (_Float16)(w - (float)hi);
    Wt_hi[idx] = hi;
    Wt_lo[idx] = lo;
}

// ---------------- split-f16 MFMA GEMM + fused attn-logit epilogue ----------------
template <int K>
__global__ __launch_bounds__(256) void gemm_split_k(const float* __restrict__ A,
                                                    const _Float16* __restrict__ Bt_hi,
                                                    const _Float16* __restrict__ Bt_lo,
                                                    const float* __restrict__ al,
                                                    const float* __restrict__ ar,
                                                    _Float16* __restrict__ Chi,
                                                    float* __restrict__ el,
                                                    float* __restrict__ er, int M) {
    const int BM = 128, BN = 128, LDP = 40;
    __shared__ _Float16 As_hi[BM][LDP];
    __shared__ _Float16 As_lo[BM][LDP];
    __shared__ _Float16 Bs_hi[BN][LDP];
    __shared__ _Float16 Bs_lo[BN][LDP];
    int tid = threadIdx.x;
    int wave = tid >> 6, lane = tid & 63;
    int q = lane >> 4, l16 = lane & 15;
    int row0 = blockIdx.y * BM, col0 = blockIdx.x * BN;
    f32x4 acc[2][8] = {};

    for (int k0 = 0; k0 < K; k0 += 32) {
#pragma unroll
        for (int c = 0; c < 4; c++) {
            int cc = tid + c * 256;
            int r = cc >> 3, o = (cc & 7) * 4;
            int gr = row0 + r;
            float4 v = make_float4(0.f, 0.f, 0.f, 0.f);
            if (gr < M) v = *(const float4*)(A + (size_t)gr * K + k0 + o);
            f16x4 hi, lo;
            hi.x = (_Float16)v.x; lo.x = (_Float16)(v.x - (float)hi.x);
            hi.y = (_Float16)v.y; lo.y = (_Float16)(v.y - (float)hi.y);
            hi.z = (_Float16)v.z; lo.z = (_Float16)(v.z - (float)hi.z);
            hi.w = (_Float16)v.w; lo.w = (_Float16)(v.w - (float)hi.w);
            *(f16x4*)&As_hi[r][o] = hi;
            *(f16x4*)&As_lo[r][o] = lo;
        }
#pragma unroll
        for (int c = 0; c < 2; c++) {
            int cc = tid + c * 256;
            int n = cc >> 2, o = (cc & 3) * 8;
            *(f16x8*)&Bs_hi[n][o] = *(const f16x8*)(Bt_hi + (size_t)(col0 + n) * K + k0 + o);
            *(f16x8*)&Bs_lo[n][o] = *(const f16x8*)(Bt_lo + (size_t)(col0 + n) * K + k0 + o);
        }
        __syncthreads();

        f16x8 ah[2], alo2[2];
#pragma unroll
        for (int ms = 0; ms < 2; ms++) {
            int m = wave * 32 + ms * 16 + l16;
            ah[ms] = *(const f16x8*)&As_hi[m][q * 8];
            alo2[ms] = *(const f16x8*)&As_lo[m][q * 8];
        }
#pragma unroll
        for (int ns = 0; ns < 8; ns++) {
            int n = ns * 16 + l16;
            f16x8 bh = *(const f16x8*)&Bs_hi[n][q * 8];
            f16x8 bl = *(const f16x8*)&Bs_lo[n][q * 8];
#pragma unroll
            for (int ms = 0; ms < 2; ms++) {
                acc[ms][ns] = __builtin_amdgcn_mfma_f32_16x16x32_f16(ah[ms], bh, acc[ms][ns], 0, 0, 0);
                acc[ms][ns] = __builtin_amdgcn_mfma_f32_16x16x32_f16(ah[ms], bl, acc[ms][ns], 0, 0, 0);
                acc[ms][ns] = __builtin_amdgcn_mfma_f32_16x16x32_f16(alo2[ms], bh, acc[ms][ns], 0, 0, 0);
            }
        }
        __syncthreads();
    }

    const int h0 = col0 >> 6;
    float alv[8], arv[8];
#pragma unroll
    for (int ns = 0; ns < 8; ns++) {
        int hh = h0 + (ns >> 2);
        int d = (ns & 3) * 16 + l16;
        alv[ns] = al[hh * 64 + d];
        arv[ns] = ar[hh * 64 + d];
    }
#pragma unroll
    for (int ms = 0; ms < 2; ms++) {
#pragma unroll
        for (int i = 0; i < 4; i++) {
            int r = row0 + wave * 32 + ms * 16 + q * 4 + i;
            bool ok = r < M;
            float el0 = 0.f, er0 = 0.f, el1 = 0.f, er1 = 0.f;
#pragma unroll
            for (int ns = 0; ns < 8; ns++) {
                float v = acc[ms][ns][i];
                if (ok) Chi[(size_t)r * HD + col0 + ns * 16 + l16] = (_Float16)v;
                if (ns < 4) { el0 = fmaf(v, alv[ns], el0); er0 = fmaf(v, arv[ns], er0); }
                else        { el1 = fmaf(v, alv[ns], el1); er1 = fmaf(v, arv[ns], er1); }
            }
#pragma unroll
            for (int off = 1; off < 16; off <<= 1) {
                el0 += __shfl_xor(el0, off, 64);
                er0 += __shfl_xor(er0, off, 64);
                el1 += __shfl_xor(el1, off, 64);
                er1 += __shfl_xor(er1, off, 64);
            }
            if (l16 == 0 && ok) {
                el[(size_t)r * 4 + h0] = el0;
                el[(size_t)r * 4 + h0 + 1] = el1;
                er[(size_t)r * 4 + h0] = er0;
                er[(size_t)r * 4 + h0 + 1] = er1;
            }
        }
    }
}

// ---------------- GAT aggregation: two-phase softmax, deferred normalization ----------------
// OUT=0: write fp32 x. OUT=1: also fused sigmoid score (layer 3).
template <int OUT>
__global__ __launch_bounds__(256) void gat_aggregate_k(const _Float16* __restrict__ hb,
                                                       const float* __restrict__ el,
                                                       const float* __restrict__ er,
                                                       const int* __restrict__ csr_src,
                                                       const int* __restrict__ row_ptr,
                                                       const float* __restrict__ bias,
                                                       float* __restrict__ xout,
                                                       const float* __restrict__ sw,
                                                       const float* __restrict__ sb,
                                                       float* __restrict__ wsc) {
    __shared__ float wlds[4][64][4];  // unnormalized exp weights [wave][edge][head]
    __shared__ int snlds[4][64];
    int wv = threadIdx.x >> 6;
    int lane = threadIdx.x & 63;
    int v = blockIdx.x * 4 + wv;
    bool valid = v < N_NODES;
    int vc = valid ? v : 0;
    int rs = row_ptr[vc];
    int deg = valid ? row_ptr[vc + 1] - rs : 0;
    float4 erv = make_float4(0.f, 0.f, 0.f, 0.f);
    if (valid) erv = *(const float4*)(er + (size_t)vc * 4);

    int head = lane >> 4;
    float inv_den = 1.f;
    float m_h = 0.f, er_h = 0.f;  // slow-path state

    if (deg <= 64) {
        // phase 1: per-lane logits (lane t = edge t)
        float e0 = -1e30f, e1 = -1e30f, e2 = -1e30f, e3 = -1e30f;
        int my_sn = 0;
        if (lane < deg) {
            my_sn = csr_src[rs + lane];
            float4 elv = *(const float4*)(el + (size_t)my_sn * 4);
            float t0 = elv.x + erv.x, t1 = elv.y + erv.y, t2 = elv.z + erv.z, t3 = elv.w + erv.w;
            e0 = t0 > 0.f ? t0 : 0.2f * t0;
            e1 = t1 > 0.f ? t1 : 0.2f * t1;
            e2 = t2 > 0.f ? t2 : 0.2f * t2;
            e3 = t3 > 0.f ? t3 : 0.2f * t3;
        }
        // max butterfly (cheap: no exp inside)
        float m0 = e0, m1 = e1, m2 = e2, m3 = e3;
        for (int off = 1; off < deg; off <<= 1) {
            m0 = fmaxf(m0, __shfl_xor(m0, off, 64));
            m1 = fmaxf(m1, __shfl_xor(m1, off, 64));
            m2 = fmaxf(m2, __shfl_xor(m2, off, 64));
            m3 = fmaxf(m3, __shfl_xor(m3, off, 64));
        }
        // single exp per head
        float p0 = 0.f, p1 = 0.f, p2 = 0.f, p3 = 0.f;
        if (lane < deg) {
            p0 = __expf(e0 - m0); p1 = __expf(e1 - m1);
            p2 = __expf(e2 - m2); p3 = __expf(e3 - m3);
        }
        // sum butterfly
        float s0 = p0, s1 = p1, s2 = p2, s3 = p3;
        for (int off = 1; off < deg; off <<= 1) {
            s0 += __shfl_xor(s0, off, 64);
            s1 += __shfl_xor(s1, off, 64);
            s2 += __shfl_xor(s2, off, 64);
            s3 += __shfl_xor(s3, off, 64);
        }
        // lane 0 holds complete sums; broadcast to all lanes
        float d0 = __shfl(s0, 0, 64), d1 = __shfl(s1, 0, 64);
        float d2 = __shfl(s2, 0, 64), d3 = __shfl(s3, 0, 64);
        float den = head == 0 ? d0 : head == 1 ? d1 : head == 2 ? d2 : d3;
        inv_den = 1.f / fmaxf(den, 1e-9f);
        if (lane < deg) {
            wlds[wv][lane][0] = p0;
            wlds[wv][lane][1] = p1;
            wlds[wv][lane][2] = p2;
            wlds[wv][lane][3] = p3;
            snlds[wv][lane] = my_sn;
        }
    } else {
        // slow path (deg > 64, rare): online softmax
        float m[4] = {-1e30f, -1e30f, -1e30f, -1e30f};
        float s[4] = {0.f, 0.f, 0.f, 0.f};
        for (int t = lane; t < deg; t += 64) {
            int sn = csr_src[rs + t];
            float4 elv = *(const float4*)(el + (size_t)sn * 4);
            float e[4];
            e[0] = elv.x + erv.x; e[1] = elv.y + erv.y; e[2] = elv.z + erv.z; e[3] = elv.w + erv.w;
#pragma unroll
            for (int hh = 0; hh < 4; hh++) {
                float ev = e[hh] > 0.f ? e[hh] : 0.2f * e[hh];
                float mn = fmaxf(m[hh], ev);
                s[hh] = s[hh] * __expf(m[hh] - mn) + __expf(ev - mn);
                m[hh] = mn;
            }
        }
#pragma unroll
        for (int off = 32; off >= 1; off >>= 1) {
#pragma unroll
            for (int hh = 0; hh < 4; hh++) {
                float mo = __shfl_xor(m[hh], off, 64);
                float so = __shfl_xor(s[hh], off, 64);
                float mn = fmaxf(m[hh], mo);
                s[hh] = s[hh] * __expf(m[hh] - mn) + so * __expf(mo - mn);
                m[hh] = mn;
            }
        }
        m_h = head == 0 ? m[0] : head == 1 ? m[1] : head == 2 ? m[2] : m[3];
        float den = head == 0 ? s[0] : head == 1 ? s[1] : head == 2 ? s[2] : s[3];
        er_h = head == 0 ? erv.x : head == 1 ? erv.y : head == 2 ? erv.z : erv.w;
        inv_den = 1.f / fmaxf(den, 1e-9f);
    }
    __syncthreads();

    float a0 = 0.f, a1 = 0.f, a2 = 0.f, a3 = 0.f;
    if (deg <= 64) {
        int t = 0;
        for (; t + 8 <= deg; t += 8) {
            int sn[8];
            float w[8];
#pragma unroll
            for (int u = 0; u < 8; u++) {
                sn[u] = snlds[wv][t + u];
                w[u] = wlds[wv][t + u][head];
            }
            f16x4 hv[8];
#pragma unroll
            for (int u = 0; u < 8; u++)
                hv[u] = *(const f16x4*)(hb + (size_t)sn[u] * HD + lane * 4);
#pragma unroll
            for (int u = 0; u < 8; u++) {
                a0 = fmaf(w[u], (float)hv[u].x, a0);
                a1 = fmaf(w[u], (float)hv[u].y, a1);
                a2 = fmaf(w[u], (float)hv[u].z, a2);
                a3 = fmaf(w[u], (float)hv[u].w, a3);
            }
        }
        for (; t < deg; t++) {
            int sn = snlds[wv][t];
            float w = wlds[wv][t][head];
            f16x4 hv = *(const f16x4*)(hb + (size_t)sn * HD + lane * 4);
            a0 = fmaf(w, (float)hv.x, a0);
            a1 = fmaf(w, (float)hv.y, a1);
            a2 = fmaf(w, (float)hv.z, a2);
            a3 = fmaf(w, (float)hv.w, a3);
        }
    } else {
        for (int t = 0; t < deg; t++) {
            int sn = csr_src[rs + t];
            float e = el[(size_t)sn * 4 + head] + er_h;
            e = e > 0.f ? e : 0.2f * e;
            float w = __expf(e - m_h);
            f16x4 hv = *(const f16x4*)(hb + (size_t)sn * HD + lane * 4);
            a0 = fmaf(w, (float)hv.x, a0);
            a1 = fmaf(w, (float)hv.y, a1);
            a2 = fmaf(w, (float)hv.z, a2);
            a3 = fmaf(w, (float)hv.w, a3);
        }
    }
    // deferred normalization + bias + selu
    float4 bv = *(const float4*)(bias + lane * 4);
    float4 o;
    o.x = selu_f(fmaf(a0, inv_den, bv.x));
    o.y = selu_f(fmaf(a1, inv_den, bv.y));
    o.z = selu_f(fmaf(a2, inv_den, bv.z));
    o.w = selu_f(fmaf(a3, inv_den, bv.w));
    if (valid) *(float4*)(xout + (size_t)v * HD + lane * 4) = o;

    if constexpr (OUT == 1) {
        // fused WeightedAverage score: sigmoid(x . sw + sb)
        float4 sv = *(const float4*)(sw + lane * 4);
        float p = o.x * sv.x + o.y * sv.y + o.z * sv.z + o.w * sv.w;
#pragma unroll
        for (int off = 1; off < 64; off <<= 1) p += __shfl_xor(p, off, 64);
        if (lane == 0 && valid) wsc[v] = 1.f / (1.f + __expf(-(p + sb[0])));
    }
}

// ---------------- readout ----------------
__global__ __launch_bounds__(256) void readout_k(const float* __restrict__ x,
                                                 const float* __restrict__ wsc,
                                                 const int* __restrict__ gstart,
                                                 const float* __restrict__ fg,
                                                 float* __restrict__ y0) {
    int g = blockIdx.x;
    int f = threadIdx.x;
    int s = gstart[g], e = gstart[g + 1];
    float num = 0.f, den = 0.f;
#pragma unroll 4
    for (int n = s; n < e; n++) {
        float wn = wsc[n];
        num = fmaf(wn, x[(size_t)n * HD + f], num);
        den += wn;
    }
    float emb = num / fmaxf(den, 1e-9f);
    y0[(size_t)g * 272 + f] = emb;
    if (f < EXTRA) y0[(size_t)g * 272 + 256 + f] = fg[g * EXTRA + f];
}

__global__ __launch_bounds__(128) void mlp_k(const float* __restrict__ y0g,
                                             const float* __restrict__ lw1, const float* __restrict__ lb1,
                                             const float* __restrict__ lw2, const float* __restrict__ lb2,
                                             const float* __restrict__ lw3, const float* __restrict__ lb3,
                                             float* __restrict__ out) {
    __shared__ float y0s[272];
    __shared__ float y1s[128];
    int g = blockIdx.x, t = threadIdx.x;
    for (int i = t; i < 272; i += 128) y0s[i] = y0g[(size_t)g * 272 + i];
    __syncthreads();
    float acc = lb1[t];
    for (int k = 0; k < 272; k++) acc = fmaf(y0s[k], lw1[k * 128 + t], acc);
    y1s[t] = selu_f(acc);
    __syncthreads();
    if (t < 64) {
        float a2 = lb2[t];
        for (int k = 0; k < 128; k++) a2 = fmaf(y1s[k], lw2[k * 64 + t], a2);
        float v2 = selu_f(a2);
        float p = v2 * lw3[t];
#pragma unroll
        for (int off = 1; off < 64; off <<= 1) p += __shfl_xor(p, off, 64);
        if (t == 0) out[g] = p + lb3[0];
    }
}

extern "C" void kernel_launch(void* const* d_in, const int* in_sizes, int n_in,
                              void* d_out, int out_size, void* d_ws, size_t ws_size,
                              hipStream_t stream) {
    const int* src = (const int*)d_in[0];
    const int* dst = (const int*)d_in[1];
    const int* node_graph = (const int*)d_in[2];
    const float* feats_node = (const float*)d_in[3];
    const float* feats_graph = (const float*)d_in[4];
    const float* W1 = (const float*)d_in[5];
    const float* al1 = (const float*)d_in[6];
    const float* ar1 = (const float*)d_in[7];
    const float* bg1 = (const float*)d_in[8];
    const float* W2 = (const float*)d_in[9];
    const float* al2 = (const float*)d_in[10];
    const float* ar2 = (const float*)d_in[11];
    const float* bg2 = (const float*)d_in[12];
    const float* W3 = (const float*)d_in[13];
    const float* al3 = (const float*)d_in[14];
    const float* ar3 = (const float*)d_in[15];
    const float* bg3 = (const float*)d_in[16];
    const float* sw = (const float*)d_in[17];
    const float* sb = (const float*)d_in[18];
    const float* lw1 = (const float*)d_in[19];
    const float* lb1 = (const float*)d_in[20];
    const float* lw2 = (const float*)d_in[21];
    const float* lb2 = (const float*)d_in[22];
    const float* lw3 = (const float*)d_in[23];
    const float* lb3 = (const float*)d_in[24];
    float* out = (float*)d_out;

    char* ws = (char*)d_ws;
    size_t off = 0;
    auto alloc = [&](size_t bytes) -> char* {
        char* p = ws + off;
        off += (bytes + 255) & ~(size_t)255;
        return p;
    };
    float* xf32 = (float*)alloc((size_t)N_NODES * HD * 4);            // x (fp32)
    _Float16* hhi = (_Float16*)alloc((size_t)N_NODES * HD * 2);       // h (f16 hi)
    _Float16* W1hi = (_Float16*)alloc((size_t)F_IN * HD * 2);
    _Float16* W1lo = (_Float16*)alloc((size_t)F_IN * HD * 2);
    _Float16* W2hi = (_Float16*)alloc((size_t)HD * HD * 2);
    _Float16* W2lo = (_Float16*)alloc((size_t)HD * HD * 2);
    _Float16* W3hi = (_Float16*)alloc((size_t)HD * HD * 2);
    _Float16* W3lo = (_Float16*)alloc((size_t)HD * HD * 2);
    float* el = (float*)alloc((size_t)N_NODES * 4 * 4);
    float* er = (float*)alloc((size_t)N_NODES * 4 * 4);
    float* wsc = (float*)alloc((size_t)N_NODES * 4);
    float* y0 = (float*)alloc((size_t)N_GRAPHS * 272 * 4);
    int* hist = (int*)alloc((size_t)N_NODES * 4);
    int* row_ptr = (int*)alloc((size_t)(N_NODES + 1) * 4);
    int* cursor = (int*)alloc((size_t)N_NODES * 4);
    int* csr_src = (int*)alloc((size_t)N_EDGES * 4);
    int* gstart = (int*)alloc((size_t)(N_GRAPHS + 1) * 4);
    int* bsums = (int*)alloc(256 * 4);
    (void)ws_size; (void)in_sizes; (void)n_in; (void)out_size;

    hipMemsetAsync(hist, 0, (size_t)N_NODES * 4, stream);
    hipMemsetAsync(cursor, 0, (size_t)N_NODES * 4, stream);

    // CSR build (by dst)
    hist_k<<<(N_EDGES + 255) / 256, 256, 0, stream>>>(dst, hist);
    int nb = (N_NODES + SCAN_BLOCK - 1) / SCAN_BLOCK;
    scan1_k<<<nb, SCAN_BLOCK, 0, stream>>>(hist, row_ptr, bsums);
    scan2_k<<<1, 256, 0, stream>>>(bsums, nb);
    scan3_k<<<(N_NODES + 255) / 256, 256, 0, stream>>>(row_ptr, bsums);
    scatter_k<<<(N_EDGES + 255) / 256, 256, 0, stream>>>(src, dst, row_ptr, cursor, csr_src);
    gbound_k<<<3, 256, 0, stream>>>(node_graph, gstart);

    // weight splits
    tcast_split_k<<<(F_IN * HD + 255) / 256, 256, 0, stream>>>(W1, W1hi, W1lo, F_IN);
    tcast_split_k<<<(HD * HD + 255) / 256, 256, 0, stream>>>(W2, W2hi, W2lo, HD);
    tcast_split_k<<<(HD * HD + 255) / 256, 256, 0, stream>>>(W3, W3hi, W3lo, HD);

    dim3 ggrid(HD / 128, (N_NODES + 127) / 128);
    int nwb = (N_NODES + 3) / 4;

    // layer 1
    gemm_split_k<F_IN><<<ggrid, 256, 0, stream>>>(feats_node, W1hi, W1lo, al1, ar1, hhi, el, er, N_NODES);
    gat_aggregate_k<0><<<nwb, 256, 0, stream>>>(hhi, el, er, csr_src, row_ptr, bg1, xf32, nullptr, nullptr, nullptr);
    // layer 2
    gemm_split_k<HD><<<ggrid, 256, 0, stream>>>(xf32, W2hi, W2lo, al2, ar2, hhi, el, er, N_NODES);
    gat_aggregate_k<0><<<nwb, 256, 0, stream>>>(hhi, el, er, csr_src, row_ptr, bg2, xf32, nullptr, nullptr, nullptr);
    // layer 3 (fused sigmoid score)
    gemm_split_k<HD><<<ggrid, 256, 0, stream>>>(xf32, W3hi, W3lo, al3, ar3, hhi, el, er, N_NODES);
    gat_aggregate_k<1><<<nwb, 256, 0, stream>>>(hhi, el, er, csr_src, row_ptr, bg3, xf32, sw, sb, wsc);

    // readout + MLP
    readout_k<<<N_GRAPHS, 256, 0, stream>>>(xf32, wsc, gstart, feats_graph, y0);
    mlp_k<<<N_GRAPHS, 128, 0, stream>>>(y0, lw1, lb1, lw2, lb2, lw3, lb3, out);
}

// Round 7
// 952.784 us; speedup vs baseline: 1.9271x; 1.0212x over previous
//
#include <hip/hip_runtime.h>

#define N_NODES 100000
#define N_EDGES 1600000
#define N_GRAPHS 512
#define F_IN 64
#define HD 256
#define EXTRA 16
#define SCAN_BLOCK 512

typedef float f32x4 __attribute__((ext_vector_type(4)));
typedef _Float16 f16x4 __attribute__((ext_vector_type(4)));
typedef _Float16 f16x8 __attribute__((ext_vector_type(8)));

__device__ __forceinline__ float selu_f(float x) {
    const float a = 1.6732632423543772f, sc = 1.0507009873554805f;
    return x > 0.f ? sc * x : sc * a * (__expf(x) - 1.f);
}

// ---------------- CSR build ----------------
__global__ __launch_bounds__(256) void hist_k(const int* __restrict__ dst, int* __restrict__ hist) {
    int j = blockIdx.x * 256 + threadIdx.x;
    if (j < N_EDGES) atomicAdd(&hist[dst[j]], 1);
}

__global__ __launch_bounds__(SCAN_BLOCK) void scan1_k(const int* __restrict__ hist,
                                                      int* __restrict__ row_ptr,
                                                      int* __restrict__ bsums) {
    __shared__ int sm[SCAN_BLOCK];
    int t = threadIdx.x;
    int i = blockIdx.x * SCAN_BLOCK + t;
    int v = (i < N_NODES) ? hist[i] : 0;
    sm[t] = v;
    __syncthreads();
    for (int off = 1; off < SCAN_BLOCK; off <<= 1) {
        int add = (t >= off) ? sm[t - off] : 0;
        __syncthreads();
        sm[t] += add;
        __syncthreads();
    }
    if (i < N_NODES) row_ptr[i] = sm[t] - v;
    if (t == SCAN_BLOCK - 1) bsums[blockIdx.x] = sm[t];
}

__global__ __launch_bounds__(256) void scan2_k(int* __restrict__ bsums, int nb) {
    __shared__ int sm[256];
    int t = threadIdx.x;
    int v = (t < nb) ? bsums[t] : 0;
    sm[t] = v;
    __syncthreads();
    for (int off = 1; off < 256; off <<= 1) {
        int add = (t >= off) ? sm[t - off] : 0;
        __syncthreads();
        sm[t] += add;
        __syncthreads();
    }
    if (t < nb) bsums[t] = sm[t] - v;
}

// finalizes row_ptr AND initializes cursor = row_ptr (absolute offsets for scatter)
__global__ __launch_bounds__(256) void scan3_k(int* __restrict__ row_ptr, const int* __restrict__ bsums,
                                               int* __restrict__ cursor) {
    int i = blockIdx.x * 256 + threadIdx.x;
    if (i < N_NODES) {
        int r = row_ptr[i] + bsums[i / SCAN_BLOCK];
        row_ptr[i] = r;
        cursor[i] = r;
    }
    if (i == 0) row_ptr[N_NODES] = N_EDGES;
}

__global__ __launch_bounds__(256) void scatter_k(const int* __restrict__ src,
                                                 const int* __restrict__ dst,
                                                 int* __restrict__ cursor,
                                                 int* __restrict__ csr_src) {
    int j = blockIdx.x * 256 + threadIdx.x;
    if (j < N_EDGES) {
        int r = atomicAdd(&cursor[dst[j]], 1);
        csr_src[r] = src[j];
    }
}

__global__ __launch_bounds__(256) void gbound_k(const int* __restrict__ node_graph, int* __restrict__ gstart) {
    int g = blockIdx.x * 256 + threadIdx.x;
    if (g > N_GRAPHS) return;
    int lo = 0, hi = N_NODES;
    while (lo < hi) {
        int mid = (lo + hi) >> 1;
        if (node_graph[mid] < g) lo = mid + 1; else hi = mid;
    }
    gstart[g] = lo;
}

// ---------------- splits/casts ----------------
__global__ __launch_bounds__(256) void tcast_split_k(const float* __restrict__ W,
                                                     _Float16* __restrict__ Wt_hi,
                                                     _Float16* __restrict__ Wt_lo, int K) {
    int idx = blockIdx.x * 256 + threadIdx.x;
    if (idx >= K * HD) return;
    int n = idx / K, k = idx - n * K;
    float w = W[(size_t)k * HD + n];
    _Float16 hi = (_Float16)w;
    _Float16 lo = (_Float16)(w - (float)hi);
    Wt_hi[idx] = hi;
    Wt_lo[idx] = lo;
}

__global__ __launch_bounds__(256) void split_cast_k(const float* __restrict__ in,
                                                    _Float16* __restrict__ hi,
                                                    _Float16* __restrict__ lo, int n4) {
    int i = blockIdx.x * 256 + threadIdx.x;
    if (i >= n4) return;
    float4 v = *(const float4*)(in + (size_t)i * 4);
    f16x4 h, l;
    h.x = (_Float16)v.x; l.x = (_Float16)(v.x - (float)h.x);
    h.y = (_Float16)v.y; l.y = (_Float16)(v.y - (float)h.y);
    h.z = (_Float16)v.z; l.z = (_Float16)(v.z - (float)h.z);
    h.w = (_Float16)v.w; l.w = (_Float16)(v.w - (float)h.w);
    *(f16x4*)(hi + (size_t)i * 4) = h;
    *(f16x4*)(lo + (size_t)i * 4) = l;
}

// ---------------- split-f16 MFMA GEMM + fused attn-logit epilogue ----------------
// A pre-split hi/lo f16 [M,K]; 3-pass: Ahi*Bhi + Ahi*Blo + Alo*Bhi (fp32 acc ~ fp32-exact)
template <int K>
__global__ __launch_bounds__(256) void gemm_split_k(const _Float16* __restrict__ Ahi,
                                                    const _Float16* __restrict__ Alo,
                                                    const _Float16* __restrict__ Bt_hi,
                                                    const _Float16* __restrict__ Bt_lo,
                                                    const float* __restrict__ al,
                                                    const float* __restrict__ ar,
                                                    _Float16* __restrict__ Chi,
                                                    float* __restrict__ el,
                                                    float* __restrict__ er, int M) {
    const int BM = 128, BN = 128, LDP = 40;
    __shared__ _Float16 As_hi[BM][LDP];
    __shared__ _Float16 As_lo[BM][LDP];
    __shared__ _Float16 Bs_hi[BN][LDP];
    __shared__ _Float16 Bs_lo[BN][LDP];
    int tid = threadIdx.x;
    int wave = tid >> 6, lane = tid & 63;
    int q = lane >> 4, l16 = lane & 15;
    int row0 = blockIdx.y * BM, col0 = blockIdx.x * BN;
    f32x4 acc[2][8] = {};

    for (int k0 = 0; k0 < K; k0 += 32) {
        // stage A hi/lo: 128 rows x 32 f16, f16x8 chunks
#pragma unroll
        for (int c = 0; c < 2; c++) {
            int cc = tid + c * 256;
            int r = cc >> 2, o = (cc & 3) * 8;
            int gr = row0 + r;
            f16x8 vh = {}, vl = {};
            if (gr < M) {
                vh = *(const f16x8*)(Ahi + (size_t)gr * K + k0 + o);
                vl = *(const f16x8*)(Alo + (size_t)gr * K + k0 + o);
            }
            *(f16x8*)&As_hi[r][o] = vh;
            *(f16x8*)&As_lo[r][o] = vl;
        }
#pragma unroll
        for (int c = 0; c < 2; c++) {
            int cc = tid + c * 256;
            int n = cc >> 2, o = (cc & 3) * 8;
            *(f16x8*)&Bs_hi[n][o] = *(const f16x8*)(Bt_hi + (size_t)(col0 + n) * K + k0 + o);
            *(f16x8*)&Bs_lo[n][o] = *(const f16x8*)(Bt_lo + (size_t)(col0 + n) * K + k0 + o);
        }
        __syncthreads();

        f16x8 ah[2], alo2[2];
#pragma unroll
        for (int ms = 0; ms < 2; ms++) {
            int m = wave * 32 + ms * 16 + l16;
            ah[ms] = *(const f16x8*)&As_hi[m][q * 8];
            alo2[ms] = *(const f16x8*)&As_lo[m][q * 8];
        }
#pragma unroll
        for (int ns = 0; ns < 8; ns++) {
            int n = ns * 16 + l16;
            f16x8 bh = *(const f16x8*)&Bs_hi[n][q * 8];
            f16x8 bl = *(const f16x8*)&Bs_lo[n][q * 8];
#pragma unroll
            for (int ms = 0; ms < 2; ms++) {
                acc[ms][ns] = __builtin_amdgcn_mfma_f32_16x16x32_f16(ah[ms], bh, acc[ms][ns], 0, 0, 0);
                acc[ms][ns] = __builtin_amdgcn_mfma_f32_16x16x32_f16(ah[ms], bl, acc[ms][ns], 0, 0, 0);
                acc[ms][ns] = __builtin_amdgcn_mfma_f32_16x16x32_f16(alo2[ms], bh, acc[ms][ns], 0, 0, 0);
            }
        }
        __syncthreads();
    }

    const int h0 = col0 >> 6;
    float alv[8], arv[8];
#pragma unroll
    for (int ns = 0; ns < 8; ns++) {
        int hh = h0 + (ns >> 2);
        int d = (ns & 3) * 16 + l16;
        alv[ns] = al[hh * 64 + d];
        arv[ns] = ar[hh * 64 + d];
    }
#pragma unroll
    for (int ms = 0; ms < 2; ms++) {
#pragma unroll
        for (int i = 0; i < 4; i++) {
            int r = row0 + wave * 32 + ms * 16 + q * 4 + i;
            bool ok = r < M;
            float el0 = 0.f, er0 = 0.f, el1 = 0.f, er1 = 0.f;
#pragma unroll
            for (int ns = 0; ns < 8; ns++) {
                float v = acc[ms][ns][i];
                if (ok) Chi[(size_t)r * HD + col0 + ns * 16 + l16] = (_Float16)v;
                if (ns < 4) { el0 = fmaf(v, alv[ns], el0); er0 = fmaf(v, arv[ns], er0); }
                else        { el1 = fmaf(v, alv[ns], el1); er1 = fmaf(v, arv[ns], er1); }
            }
#pragma unroll
            for (int off = 1; off < 16; off <<= 1) {
                el0 += __shfl_xor(el0, off, 64);
                er0 += __shfl_xor(er0, off, 64);
                el1 += __shfl_xor(el1, off, 64);
                er1 += __shfl_xor(er1, off, 64);
            }
            if (l16 == 0 && ok) {
                el[(size_t)r * 4 + h0] = el0;
                el[(size_t)r * 4 + h0 + 1] = el1;
                er[(size_t)r * 4 + h0] = er0;
                er[(size_t)r * 4 + h0 + 1] = er1;
            }
        }
    }
}

// ---------------- GAT aggregation ----------------
// OUT=0: write x as hi/lo f16 split (feeds next GEMM). OUT=1: write fp32 x + fused sigmoid score.
// Wave-private LDS slices -> NO block barrier anywhere.
template <int OUT>
__global__ __launch_bounds__(256) void gat_aggregate_k(const _Float16* __restrict__ hb,
                                                       const float* __restrict__ el,
                                                       const float* __restrict__ er,
                                                       const int* __restrict__ csr_src,
                                                       const int* __restrict__ row_ptr,
                                                       const float* __restrict__ bias,
                                                       _Float16* __restrict__ xhi,
                                                       _Float16* __restrict__ xlo,
                                                       float* __restrict__ xf32,
                                                       const float* __restrict__ sw,
                                                       const float* __restrict__ sb,
                                                       float* __restrict__ wsc) {
    __shared__ float wlds[4][64][4];  // unnormalized exp weights [wave][edge][head]
    __shared__ int snlds[4][64];
    int wv = threadIdx.x >> 6;
    int lane = threadIdx.x & 63;
    int v = blockIdx.x * 4 + wv;
    bool valid = v < N_NODES;
    int vc = valid ? v : 0;
    int rs = row_ptr[vc];
    int deg = valid ? row_ptr[vc + 1] - rs : 0;
    float4 erv = make_float4(0.f, 0.f, 0.f, 0.f);
    if (valid) erv = *(const float4*)(er + (size_t)vc * 4);

    int head = lane >> 4;
    float inv_den = 1.f;
    float m_h = 0.f, er_h = 0.f;  // slow-path state
    f16x4 hv_pre[8];
    int nb0 = 0;

    if (deg <= 64) {
        // phase 1: per-lane logits (lane t = edge t)
        float e0 = -1e30f, e1 = -1e30f, e2 = -1e30f, e3 = -1e30f;
        int my_sn = 0;
        if (lane < deg) {
            my_sn = csr_src[rs + lane];
            float4 elv = *(const float4*)(el + (size_t)my_sn * 4);
            float t0 = elv.x + erv.x, t1 = elv.y + erv.y, t2 = elv.z + erv.z, t3 = elv.w + erv.w;
            e0 = t0 > 0.f ? t0 : 0.2f * t0;
            e1 = t1 > 0.f ? t1 : 0.2f * t1;
            e2 = t2 > 0.f ? t2 : 0.2f * t2;
            e3 = t3 > 0.f ? t3 : 0.2f * t3;
        }
        // prefetch batch-0 h rows NOW; latency hides behind the softmax reduction
        nb0 = deg < 8 ? deg : 8;
#pragma unroll
        for (int u = 0; u < 8; u++) {
            int snb = __shfl(my_sn, u, 64);
            if (u < nb0) hv_pre[u] = *(const f16x4*)(hb + (size_t)snb * HD + lane * 4);
        }
        // max butterfly
        float m0 = e0, m1 = e1, m2 = e2, m3 = e3;
        for (int off = 1; off < deg; off <<= 1) {
            m0 = fmaxf(m0, __shfl_xor(m0, off, 64));
            m1 = fmaxf(m1, __shfl_xor(m1, off, 64));
            m2 = fmaxf(m2, __shfl_xor(m2, off, 64));
            m3 = fmaxf(m3, __shfl_xor(m3, off, 64));
        }
        // one exp per head
        float p0 = 0.f, p1 = 0.f, p2 = 0.f, p3 = 0.f;
        if (lane < deg) {
            p0 = __expf(e0 - m0); p1 = __expf(e1 - m1);
            p2 = __expf(e2 - m2); p3 = __expf(e3 - m3);
        }
        // sum butterfly
        float s0 = p0, s1 = p1, s2 = p2, s3 = p3;
        for (int off = 1; off < deg; off <<= 1) {
            s0 += __shfl_xor(s0, off, 64);
            s1 += __shfl_xor(s1, off, 64);
            s2 += __shfl_xor(s2, off, 64);
            s3 += __shfl_xor(s3, off, 64);
        }
        float d0 = __shfl(s0, 0, 64), d1 = __shfl(s1, 0, 64);
        float d2 = __shfl(s2, 0, 64), d3 = __shfl(s3, 0, 64);
        float den = head == 0 ? d0 : head == 1 ? d1 : head == 2 ? d2 : d3;
        inv_den = 1.f / fmaxf(den, 1e-9f);
        if (lane < deg) {
            wlds[wv][lane][0] = p0;
            wlds[wv][lane][1] = p1;
            wlds[wv][lane][2] = p2;
            wlds[wv][lane][3] = p3;
            snlds[wv][lane] = my_sn;
        }
        // no barrier: wave-private LDS slice; lgkmcnt ordering suffices
    } else {
        // slow path (deg > 64, rare): online softmax
        float m[4] = {-1e30f, -1e30f, -1e30f, -1e30f};
        float s[4] = {0.f, 0.f, 0.f, 0.f};
        for (int t = lane; t < deg; t += 64) {
            int sn = csr_src[rs + t];
            float4 elv = *(const float4*)(el + (size_t)sn * 4);
            float e[4];
            e[0] = elv.x + erv.x; e[1] = elv.y + erv.y; e[2] = elv.z + erv.z; e[3] = elv.w + erv.w;
#pragma unroll
            for (int hh = 0; hh < 4; hh++) {
                float ev = e[hh] > 0.f ? e[hh] : 0.2f * e[hh];
                float mn = fmaxf(m[hh], ev);
                s[hh] = s[hh] * __expf(m[hh] - mn) + __expf(ev - mn);
                m[hh] = mn;
            }
        }
#pragma unroll
        for (int off = 32; off >= 1; off >>= 1) {
#pragma unroll
            for (int hh = 0; hh < 4; hh++) {
                float mo = __shfl_xor(m[hh], off, 64);
                float so = __shfl_xor(s[hh], off, 64);
                float mn = fmaxf(m[hh], mo);
                s[hh] = s[hh] * __expf(m[hh] - mn) + so * __expf(mo - mn);
                m[hh] = mn;
            }
        }
        m_h = head == 0 ? m[0] : head == 1 ? m[1] : head == 2 ? m[2] : m[3];
        float den = head == 0 ? s[0] : head == 1 ? s[1] : head == 2 ? s[2] : s[3];
        er_h = head == 0 ? erv.x : head == 1 ? erv.y : head == 2 ? erv.z : erv.w;
        inv_den = 1.f / fmaxf(den, 1e-9f);
    }

    float a0 = 0.f, a1 = 0.f, a2 = 0.f, a3 = 0.f;
    if (deg <= 64) {
        // batch 0 from prefetched registers
#pragma unroll
        for (int u = 0; u < 8; u++) {
            if (u < nb0) {
                float w = wlds[wv][u][head];
                a0 = fmaf(w, (float)hv_pre[u].x, a0);
                a1 = fmaf(w, (float)hv_pre[u].y, a1);
                a2 = fmaf(w, (float)hv_pre[u].z, a2);
                a3 = fmaf(w, (float)hv_pre[u].w, a3);
            }
        }
        int t = 8;
        for (; t + 8 <= deg; t += 8) {
            int sn[8];
            float w[8];
#pragma unroll
            for (int u = 0; u < 8; u++) {
                sn[u] = snlds[wv][t + u];
                w[u] = wlds[wv][t + u][head];
            }
            f16x4 hv[8];
#pragma unroll
            for (int u = 0; u < 8; u++)
                hv[u] = *(const f16x4*)(hb + (size_t)sn[u] * HD + lane * 4);
#pragma unroll
            for (int u = 0; u < 8; u++) {
                a0 = fmaf(w[u], (float)hv[u].x, a0);
                a1 = fmaf(w[u], (float)hv[u].y, a1);
                a2 = fmaf(w[u], (float)hv[u].z, a2);
                a3 = fmaf(w[u], (float)hv[u].w, a3);
            }
        }
        for (; t < deg; t++) {
            int sn = snlds[wv][t];
            float w = wlds[wv][t][head];
            f16x4 hv = *(const f16x4*)(hb + (size_t)sn * HD + lane * 4);
            a0 = fmaf(w, (float)hv.x, a0);
            a1 = fmaf(w, (float)hv.y, a1);
            a2 = fmaf(w, (float)hv.z, a2);
            a3 = fmaf(w, (float)hv.w, a3);
        }
    } else {
        for (int t = 0; t < deg; t++) {
            int sn = csr_src[rs + t];
            float e = el[(size_t)sn * 4 + head] + er_h;
            e = e > 0.f ? e : 0.2f * e;
            float w = __expf(e - m_h);
            f16x4 hv = *(const f16x4*)(hb + (size_t)sn * HD + lane * 4);
            a0 = fmaf(w, (float)hv.x, a0);
            a1 = fmaf(w, (float)hv.y, a1);
            a2 = fmaf(w, (float)hv.z, a2);
            a3 = fmaf(w, (float)hv.w, a3);
        }
    }
    // deferred normalization + bias + selu
    float4 bv = *(const float4*)(bias + lane * 4);
    float4 o;
    o.x = selu_f(fmaf(a0, inv_den, bv.x));
    o.y = selu_f(fmaf(a1, inv_den, bv.y));
    o.z = selu_f(fmaf(a2, inv_den, bv.z));
    o.w = selu_f(fmaf(a3, inv_den, bv.w));

    if constexpr (OUT == 0) {
        f16x4 oh, ol;
        oh.x = (_Float16)o.x; ol.x = (_Float16)(o.x - (float)oh.x);
        oh.y = (_Float16)o.y; ol.y = (_Float16)(o.y - (float)oh.y);
        oh.z = (_Float16)o.z; ol.z = (_Float16)(o.z - (float)oh.z);
        oh.w = (_Float16)o.w; ol.w = (_Float16)(o.w - (float)oh.w);
        if (valid) {
            *(f16x4*)(xhi + (size_t)v * HD + lane * 4) = oh;
            *(f16x4*)(xlo + (size_t)v * HD + lane * 4) = ol;
        }
    } else {
        if (valid) *(float4*)(xf32 + (size_t)v * HD + lane * 4) = o;
        // fused WeightedAverage score: sigmoid(x . sw + sb)
        float4 sv = *(const float4*)(sw + lane * 4);
        float p = o.x * sv.x + o.y * sv.y + o.z * sv.z + o.w * sv.w;
#pragma unroll
        for (int off = 1; off < 64; off <<= 1) p += __shfl_xor(p, off, 64);
        if (lane == 0 && valid) wsc[v] = 1.f / (1.f + __expf(-(p + sb[0])));
    }
}

// ---------------- readout ----------------
__global__ __launch_bounds__(256) void readout_k(const float* __restrict__ x,
                                                 const float* __restrict__ wsc,
                                                 const int* __restrict__ gstart,
                                                 const float* __restrict__ fg,
                                                 float* __restrict__ y0) {
    int g = blockIdx.x;
    int f = threadIdx.x;
    int s = gstart[g], e = gstart[g + 1];
    float num = 0.f, den = 0.f;
#pragma unroll 4
    for (int n = s; n < e; n++) {
        float wn = wsc[n];
        num = fmaf(wn, x[(size_t)n * HD + f], num);
        den += wn;
    }
    float emb = num / fmaxf(den, 1e-9f);
    y0[(size_t)g * 272 + f] = emb;
    if (f < EXTRA) y0[(size_t)g * 272 + 256 + f] = fg[g * EXTRA + f];
}

__global__ __launch_bounds__(128) void mlp_k(const float* __restrict__ y0g,
                                             const float* __restrict__ lw1, const float* __restrict__ lb1,
                                             const float* __restrict__ lw2, const float* __restrict__ lb2,
                                             const float* __restrict__ lw3, const float* __restrict__ lb3,
                                             float* __restrict__ out) {
    __shared__ float y0s[272];
    __shared__ float y1s[128];
    int g = blockIdx.x, t = threadIdx.x;
    for (int i = t; i < 272; i += 128) y0s[i] = y0g[(size_t)g * 272 + i];
    __syncthreads();
    float acc = lb1[t];
    for (int k = 0; k < 272; k++) acc = fmaf(y0s[k], lw1[k * 128 + t], acc);
    y1s[t] = selu_f(acc);
    __syncthreads();
    if (t < 64) {
        float a2 = lb2[t];
        for (int k = 0; k < 128; k++) a2 = fmaf(y1s[k], lw2[k * 64 + t], a2);
        float v2 = selu_f(a2);
        float p = v2 * lw3[t];
#pragma unroll
        for (int off = 1; off < 64; off <<= 1) p += __shfl_xor(p, off, 64);
        if (t == 0) out[g] = p + lb3[0];
    }
}

extern "C" void kernel_launch(void* const* d_in, const int* in_sizes, int n_in,
                              void* d_out, int out_size, void* d_ws, size_t ws_size,
                              hipStream_t stream) {
    const int* src = (const int*)d_in[0];
    const int* dst = (const int*)d_in[1];
    const int* node_graph = (const int*)d_in[2];
    const float* feats_node = (const float*)d_in[3];
    const float* feats_graph = (const float*)d_in[4];
    const float* W1 = (const float*)d_in[5];
    const float* al1 = (const float*)d_in[6];
    const float* ar1 = (const float*)d_in[7];
    const float* bg1 = (const float*)d_in[8];
    const float* W2 = (const float*)d_in[9];
    const float* al2 = (const float*)d_in[10];
    const float* ar2 = (const float*)d_in[11];
    const float* bg2 = (const float*)d_in[12];
    const float* W3 = (const float*)d_in[13];
    const float* al3 = (const float*)d_in[14];
    const float* ar3 = (const float*)d_in[15];
    const float* bg3 = (const float*)d_in[16];
    const float* sw = (const float*)d_in[17];
    const float* sb = (const float*)d_in[18];
    const float* lw1 = (const float*)d_in[19];
    const float* lb1 = (const float*)d_in[20];
    const float* lw2 = (const float*)d_in[21];
    const float* lb2 = (const float*)d_in[22];
    const float* lw3 = (const float*)d_in[23];
    const float* lb3 = (const float*)d_in[24];
    float* out = (float*)d_out;

    char* ws = (char*)d_ws;
    size_t off = 0;
    auto alloc = [&](size_t bytes) -> char* {
        char* p = ws + off;
        off += (bytes + 255) & ~(size_t)255;
        return p;
    };
    // xhi+xlo contiguous; xf32 (layer-3 output) aliases the pair (lifetimes disjoint:
    // last xhi/xlo read = layer-3 GEMM, which completes before layer-3 aggregate writes xf32)
    _Float16* xhi = (_Float16*)alloc((size_t)N_NODES * HD * 2);
    _Float16* xlo = (_Float16*)alloc((size_t)N_NODES * HD * 2);
    float* xf32 = (float*)xhi;
    _Float16* hhi = (_Float16*)alloc((size_t)N_NODES * HD * 2);       // h (f16 hi)
    _Float16* fhi = (_Float16*)alloc((size_t)N_NODES * F_IN * 2);
    _Float16* flo = (_Float16*)alloc((size_t)N_NODES * F_IN * 2);
    _Float16* W1hi = (_Float16*)alloc((size_t)F_IN * HD * 2);
    _Float16* W1lo = (_Float16*)alloc((size_t)F_IN * HD * 2);
    _Float16* W2hi = (_Float16*)alloc((size_t)HD * HD * 2);
    _Float16* W2lo = (_Float16*)alloc((size_t)HD * HD * 2);
    _Float16* W3hi = (_Float16*)alloc((size_t)HD * HD * 2);
    _Float16* W3lo = (_Float16*)alloc((size_t)HD * HD * 2);
    float* el = (float*)alloc((size_t)N_NODES * 4 * 4);
    float* er = (float*)alloc((size_t)N_NODES * 4 * 4);
    float* wsc = (float*)alloc((size_t)N_NODES * 4);
    float* y0 = (float*)alloc((size_t)N_GRAPHS * 272 * 4);
    int* hist = (int*)alloc((size_t)N_NODES * 4);
    int* row_ptr = (int*)alloc((size_t)(N_NODES + 1) * 4);
    int* cursor = (int*)alloc((size_t)N_NODES * 4);
    int* csr_src = (int*)alloc((size_t)N_EDGES * 4);
    int* gstart = (int*)alloc((size_t)(N_GRAPHS + 1) * 4);
    int* bsums = (int*)alloc(256 * 4);
    (void)ws_size; (void)in_sizes; (void)n_in; (void)out_size;

    hipMemsetAsync(hist, 0, (size_t)N_NODES * 4, stream);

    // CSR build (by dst)
    hist_k<<<(N_EDGES + 255) / 256, 256, 0, stream>>>(dst, hist);
    int nb = (N_NODES + SCAN_BLOCK - 1) / SCAN_BLOCK;
    scan1_k<<<nb, SCAN_BLOCK, 0, stream>>>(hist, row_ptr, bsums);
    scan2_k<<<1, 256, 0, stream>>>(bsums, nb);
    scan3_k<<<(N_NODES + 255) / 256, 256, 0, stream>>>(row_ptr, bsums, cursor);
    scatter_k<<<(N_EDGES + 255) / 256, 256, 0, stream>>>(src, dst, cursor, csr_src);
    gbound_k<<<3, 256, 0, stream>>>(node_graph, gstart);

    // splits
    split_cast_k<<<(N_NODES * F_IN / 4 + 255) / 256, 256, 0, stream>>>(feats_node, fhi, flo, N_NODES * F_IN / 4);
    tcast_split_k<<<(F_IN * HD + 255) / 256, 256, 0, stream>>>(W1, W1hi, W1lo, F_IN);
    tcast_split_k<<<(HD * HD + 255) / 256, 256, 0, stream>>>(W2, W2hi, W2lo, HD);
    tcast_split_k<<<(HD * HD + 255) / 256, 256, 0, stream>>>(W3, W3hi, W3lo, HD);

    dim3 ggrid(HD / 128, (N_NODES + 127) / 128);
    int nwb = (N_NODES + 3) / 4;

    // layer 1
    gemm_split_k<F_IN><<<ggrid, 256, 0, stream>>>(fhi, flo, W1hi, W1lo, al1, ar1, hhi, el, er, N_NODES);
    gat_aggregate_k<0><<<nwb, 256, 0, stream>>>(hhi, el, er, csr_src, row_ptr, bg1, xhi, xlo, nullptr, nullptr, nullptr, nullptr);
    // layer 2
    gemm_split_k<HD><<<ggrid, 256, 0, stream>>>(xhi, xlo, W2hi, W2lo, al2, ar2, hhi, el, er, N_NODES);
    gat_aggregate_k<0><<<nwb, 256, 0, stream>>>(hhi, el, er, csr_src, row_ptr, bg2, xhi, xlo, nullptr, nullptr, nullptr, nullptr);
    // layer 3 (fp32 out + fused sigmoid score)
    gemm_split_k<HD><<<ggrid, 256, 0, stream>>>(xhi, xlo, W3hi, W3lo, al3, ar3, hhi, el, er, N_NODES);
    gat_aggregate_k<1><<<nwb, 256, 0, stream>>>(hhi, el, er, csr_src, row_ptr, bg3, nullptr, nullptr, xf32, sw, sb, wsc);

    // readout + MLP
    readout_k<<<N_GRAPHS, 256, 0, stream>>>(xf32, wsc, gstart, feats_graph, y0);
    mlp_k<<<N_GRAPHS, 128, 0, stream>>>(y0, lw1, lb1, lw2, lb2, lw3, lb3, out);
}